// Round 5
// baseline (572.373 us; speedup 1.0000x reference)
//
#include <hip/hip_runtime.h>
#include <hip/hip_bf16.h>
#include <cstdint>
#include <cstddef>

typedef unsigned short u16;
typedef __attribute__((ext_vector_type(8))) short short8;   // 8 bf16 = 4 VGPRs (MFMA A/B frag)
typedef __attribute__((ext_vector_type(4))) float f32x4;    // MFMA C/D frag (16x16)
typedef __attribute__((ext_vector_type(16))) float f32x16;  // MFMA C/D frag (32x32)

__device__ __forceinline__ u16 f2bf(float f) {
    union { float f; uint32_t u; } v; v.f = f;
    uint32_t u = v.u;
    return (u16)((u + 0x7fffu + ((u >> 16) & 1u)) >> 16);   // RNE
}
__device__ __forceinline__ float bf2f(u16 u) {
    union { uint32_t u; float f; } v; v.u = ((uint32_t)u) << 16;
    return v.f;
}
// pack two f32 -> one dword of 2 bf16 (lo|hi<<16), pure bit-ops
__device__ __forceinline__ uint32_t pk2(float lo, float hi) {
    return (uint32_t)f2bf(lo) | ((uint32_t)f2bf(hi) << 16);
}

// async global->LDS 16B copy (m97: global_load_lds_dwordx4).
__device__ __forceinline__ void async_cp16(const u16* g, u16* l) {
    __builtin_amdgcn_global_load_lds(
        (const __attribute__((address_space(1))) unsigned int*)g,
        (__attribute__((address_space(3))) unsigned int*)l, 16, 0, 0);
}

// ---------------- cast fp32 -> bf16 (vectorized) ----------------
__global__ __launch_bounds__(256) void cast_f32_bf16(const float* __restrict__ in,
                                                     u16* __restrict__ out, int n) {
    int i = (blockIdx.x * 256 + threadIdx.x) * 4;
    if (i >= n) return;
    float4 v = *(const float4*)(in + i);
    ushort4 r;
    r.x = f2bf(v.x); r.y = f2bf(v.y); r.z = f2bf(v.z); r.w = f2bf(v.w);
    *(ushort4*)(out + i) = r;
}

// ---------------- W (K,N) fp32 -> Wt (N,K) bf16 (optionally pre-scaled) ----------------
__global__ __launch_bounds__(256) void transpose_cast(const float* __restrict__ W,
                                                      u16* __restrict__ Wt, int K, int N,
                                                      float smul) {
    __shared__ u16 tile[64][72];
    int kt = blockIdx.x * 64, nt = blockIdx.y * 64;
    int t = threadIdx.x;
#pragma unroll
    for (int i = 0; i < 16; i++) {
        int idx = t + i * 256; int kl = idx >> 6, nl = idx & 63;
        tile[kl][nl] = f2bf(W[(size_t)(kt + kl) * N + nt + nl] * smul);
    }
    __syncthreads();
#pragma unroll
    for (int i = 0; i < 16; i++) {
        int idx = t + i * 256; int nl = idx >> 6, kl = idx & 63;
        Wt[(size_t)(nt + nl) * K + kt + kl] = tile[kl][nl];
    }
}

// ---------------- bf16 GEMM (m97 structure), compile-time shapes ----------------
template <int OUTF32, int KDIM, int NDIM>
__global__ __launch_bounds__(256) void gemm_bt(const u16* __restrict__ A, int lda,
                                               const u16* __restrict__ Bt,
                                               void* __restrict__ Cout, int ldc) {
    __shared__ __align__(16) u16 Al[128 * 32];
    __shared__ __align__(16) u16 Bl[128 * 32];
    int m0 = blockIdx.x * 128, n0 = blockIdx.y * 128;
    int t = threadIdx.x;
    int w = t >> 6, l = t & 63;
    int lm = l & 15, lq = l >> 4;
    int wm = (w >> 1) * 64, wn = (w & 1) * 64;
    f32x4 acc[4][4] = {};

    for (int k0 = 0; k0 < KDIM; k0 += 32) {
#pragma unroll
        for (int c = 0; c < 2; c++) {
            int chunk = w * 128 + c * 64 + l;
            int row = chunk >> 2, col8 = (chunk & 3) * 8;
            async_cp16(A + (size_t)(m0 + row) * lda + k0 + col8,
                       Al + (w * 128 + c * 64) * 8);
            int brow = n0 + row;
            if (NDIM % 128 != 0) { if (brow >= NDIM) brow = NDIM - 1; }
            async_cp16(Bt + (size_t)brow * KDIM + k0 + col8,
                       Bl + (w * 128 + c * 64) * 8);
        }
        __syncthreads();
        short8 af[4], bfr[4];
#pragma unroll
        for (int mt = 0; mt < 4; mt++)
            af[mt] = *(const short8*)(Al + (wm + mt * 16 + lm) * 32 + lq * 8);
#pragma unroll
        for (int nt = 0; nt < 4; nt++)
            bfr[nt] = *(const short8*)(Bl + (wn + nt * 16 + lm) * 32 + lq * 8);
#pragma unroll
        for (int mt = 0; mt < 4; mt++)
#pragma unroll
            for (int nt = 0; nt < 4; nt++)
                acc[mt][nt] = __builtin_amdgcn_mfma_f32_16x16x32_bf16(af[mt], bfr[nt], acc[mt][nt], 0, 0, 0);
        __syncthreads();
    }
#pragma unroll
    for (int mt = 0; mt < 4; mt++) {
#pragma unroll
        for (int nt = 0; nt < 4; nt++) {
            int col = n0 + wn + nt * 16 + lm;
            if (col < NDIM) {
#pragma unroll
                for (int r = 0; r < 4; r++) {
                    int row = m0 + wm + mt * 16 + lq * 4 + r;
                    if (OUTF32) ((float*)Cout)[(size_t)row * ldc + col] = acc[mt][nt][r];
                    else        ((u16*)Cout)[(size_t)row * ldc + col] = f2bf(acc[mt][nt][r]);
                }
            }
        }
    }
}

// ---------------- RoPE in-place on (rows, nheads*64) bf16, row stride `stride` ----------------
__global__ __launch_bounds__(256) void rope_kernel(u16* __restrict__ x, int rows,
                                                   int nheads, int Smask, int stride) {
    int i = blockIdx.x * 256 + threadIdx.x;
    int total = rows * nheads * 32;
    if (i >= total) return;
    int j = i & 31;
    int h = (i >> 5) % nheads;
    int row = i / (32 * nheads);
    int pos = row & Smask;
    float f = exp2f((float)j * -0.4152410118609828f);
    float ang = (float)pos * f;
    float c = cosf(ang), s = sinf(ang);
    u16* p = x + (size_t)row * stride + h * 64 + j;
    float x1 = bf2f(p[0]), x2 = bf2f(p[32]);
    p[0]  = f2bf(x1 * c - x2 * s);
    p[32] = f2bf(x2 * c + x1 * s);
}

// ---------------- V slice of kv -> v_t (B,H,128,S) bf16 ----------------
__global__ __launch_bounds__(256) void transpose_v(const u16* __restrict__ kv,
                                                   u16* __restrict__ vt, int S) {
    __shared__ u16 tile[64][72];
    int bh = blockIdx.z; int b = bh >> 4, h = bh & 15;
    int s0 = blockIdx.x * 64, d0 = blockIdx.y * 64;
    int t = threadIdx.x;
#pragma unroll
    for (int i = 0; i < 16; i++) {
        int idx = t + i * 256; int sl = idx >> 6, dl = idx & 63;
        tile[sl][dl] = kv[(size_t)(b * S + s0 + sl) * 4096 + 2048 + h * 128 + d0 + dl];
    }
    __syncthreads();
#pragma unroll
    for (int i = 0; i < 16; i++) {
        int idx = t + i * 256; int dl = idx >> 6, sl = idx & 63;
        vt[((size_t)(bh * 128 + d0 + dl)) * S + s0 + sl] = tile[sl][dl];
    }
}

// ---------------- Flash MLA attention v9: cache-direct, zero LDS, zero barriers ----------------
// Round-4 post-mortem: v8's 1 block/CU = 1 wave/SIMD killed TLP (134us). Root conflict:
// LDS staging forces 44KB/block + barrier lockstep. But each (b,h)'s K/V set (~1.3MB)
// is XCD-pinned into a 4MB L2 (+256MB L3) -> staging is pure overhead (guide common-
// mistake #7: "stage only when data doesn't cache-fit"; m169 +26% from dropping it).
// v9 = v7's compute path (frags/softmax/P-pack/epilogue byte-identical) with A-operands
// read DIRECTLY from kvbuf/kr/v_t:
//  * no __syncthreads anywhere; each wave loops only its OWN needed K-tiles
//    (nt_w = (qrow+31)/64+1) and retires early -> imbalance heals per-wave.
//  * LDS = 0 -> occupancy VGPR-bound only (~2 waves/SIMD); grid (32,16) heavy-first
//    (qt=15-y, LPT); XCD pinning unchanged (id%8 = bh%8).
__global__ __launch_bounds__(256, 2) void mla_attn(const u16* __restrict__ qc, int qcs,
                                                   const u16* __restrict__ qr, int qrs,
                                                   const u16* __restrict__ kvbuf,
                                                   const u16* __restrict__ kr, int krs,
                                                   const u16* __restrict__ vt,
                                                   u16* __restrict__ out, int S) {
    const float NEG = -1e30f;
    int bh = blockIdx.x; int b = bh >> 4, h = bh & 15;   // XCD-pinning: XCD = bh%8
    int qt = 15 - (int)blockIdx.y;                   // heavy-first (LPT)
    int t = threadIdx.x, w = t >> 6, l = t & 63;
    int ln = l & 31, hi = l >> 5;

    int qrow = qt * 128 + w * 32;                    // this wave's 32 q-rows
    int nt_w = (qrow + 31) / 64 + 1;                 // tiles THIS WAVE needs (no barriers)

    // Q B-frags for 32x32x16: lane holds col q=ln, k = ks*16 + hi*8 + j (pre-scaled)
    short8 bq[12];
    {
        const u16* qc_row = qc + (size_t)(b * S + qrow + ln) * qcs + h * 128;
#pragma unroll
        for (int ks = 0; ks < 8; ks++) bq[ks] = *(const short8*)(qc_row + ks * 16 + hi * 8);
        const u16* qr_row = qr + (size_t)(b * S + qrow + ln) * qrs + h * 64;
#pragma unroll
        for (int ks = 0; ks < 4; ks++) bq[8 + ks] = *(const short8*)(qr_row + ks * 16 + hi * 8);
    }

    f32x16 o[4] = {};                             // O^T: 4 dim-tiles x (32x32 C)
    float m_s = 0.0f, l_s = 0.f;                  // running max (ref 0) / denom

    for (int kt = 0; kt < nt_w; kt++) {
        int kbase = kt * 64;

        // S^T: sacc[kt2][r] = S_log2[key=kbase+kt2*32+(r&3)+8(r>>2)+4hi][q=qrow+ln]
        // A-frag: row m = key = kbase + kt2*32 + ln, k-dim d = ks*16 + hi*8 (d<128 from
        // kv cols h*128+d; d>=128 from kr col d-128) — same elements v7 staged in Kl.
        const u16* k0p = kvbuf + (size_t)(b * S + kbase + ln) * 4096 + h * 128;
        const u16* k1p = k0p + (size_t)32 * 4096;
        const u16* r0p = kr + (size_t)(b * S + kbase + ln) * krs;
        const u16* r1p = r0p + (size_t)32 * krs;
        f32x16 sacc[2] = {};
        __builtin_amdgcn_s_setprio(1);
#pragma unroll
        for (int ks = 0; ks < 8; ks++) {
            short8 ak0 = *(const short8*)(k0p + ks * 16 + hi * 8);
            short8 ak1 = *(const short8*)(k1p + ks * 16 + hi * 8);
            sacc[0] = __builtin_amdgcn_mfma_f32_32x32x16_bf16(ak0, bq[ks], sacc[0], 0, 0, 0);
            sacc[1] = __builtin_amdgcn_mfma_f32_32x32x16_bf16(ak1, bq[ks], sacc[1], 0, 0, 0);
        }
#pragma unroll
        for (int ks = 8; ks < 12; ks++) {
            short8 ak0 = *(const short8*)(r0p + (ks - 8) * 16 + hi * 8);
            short8 ak1 = *(const short8*)(r1p + (ks - 8) * 16 + hi * 8);
            sacc[0] = __builtin_amdgcn_mfma_f32_32x32x16_bf16(ak0, bq[ks], sacc[0], 0, 0, 0);
            sacc[1] = __builtin_amdgcn_mfma_f32_32x32x16_bf16(ak1, bq[ks], sacc[1], 0, 0, 0);
        }
        __builtin_amdgcn_s_setprio(0);

        if (kbase + 63 > qrow) {              // diagonal tiles: causal mask (finite)
            int qi = qrow + ln;
#pragma unroll
            for (int kt2 = 0; kt2 < 2; kt2++)
#pragma unroll
                for (int r = 0; r < 16; r++) {
                    int key = kbase + kt2 * 32 + (r & 3) + 8 * (r >> 2) + 4 * hi;
                    if (key > qi) sacc[kt2][r] = NEG;
                }
        }

        // online softmax (log2 domain, ref max 0), lane pair (l, l^32) shares q-row
        float mx = NEG;
#pragma unroll
        for (int kt2 = 0; kt2 < 2; kt2++)
#pragma unroll
            for (int r = 0; r < 16; r++) mx = fmaxf(mx, sacc[kt2][r]);
        mx = fmaxf(mx, __shfl_xor(mx, 32));
        if (!__all(mx - m_s <= 8.0f)) {       // defer-max (T13): P <= 2^8 otherwise
            float mnew = fmaxf(m_s, mx);
            float alpha = exp2f(m_s - mnew);
            m_s = mnew;
            l_s *= alpha;
#pragma unroll
            for (int dt = 0; dt < 4; dt++) o[dt] *= alpha;
        }

        // P = 2^(S-m): exp + pack to bf16 B-frags in-register; cross-half via shfl_xor
        float rs = 0.f;
        short8 bp[2][2];
#pragma unroll
        for (int kt2 = 0; kt2 < 2; kt2++) {
            float p[16];
#pragma unroll
            for (int r = 0; r < 16; r++) p[r] = exp2f(sacc[kt2][r] - m_s);
#pragma unroll
            for (int r = 0; r < 16; r++) rs += p[r];
            uint32_t c0 = pk2(p[0], p[1]),  c1 = pk2(p[2], p[3]);
            uint32_t c2 = pk2(p[4], p[5]),  c3 = pk2(p[6], p[7]);
            uint32_t e0 = __shfl_xor(c0, 32), e1 = __shfl_xor(c1, 32);
            uint32_t e2 = __shfl_xor(c2, 32), e3 = __shfl_xor(c3, 32);
            union { uint32_t u[4]; short8 s; } f0;
            f0.u[0] = hi ? e2 : c0;
            f0.u[1] = hi ? e3 : c1;
            f0.u[2] = hi ? c2 : e0;
            f0.u[3] = hi ? c3 : e1;
            bp[kt2][0] = f0.s;
            uint32_t c4 = pk2(p[8], p[9]),   c5 = pk2(p[10], p[11]);
            uint32_t c6 = pk2(p[12], p[13]), c7 = pk2(p[14], p[15]);
            uint32_t e4 = __shfl_xor(c4, 32), e5 = __shfl_xor(c5, 32);
            uint32_t e6 = __shfl_xor(c6, 32), e7 = __shfl_xor(c7, 32);
            union { uint32_t u[4]; short8 s; } f1;
            f1.u[0] = hi ? e6 : c4;
            f1.u[1] = hi ? e7 : c5;
            f1.u[2] = hi ? c6 : e4;
            f1.u[3] = hi ? c7 : e5;
            bp[kt2][1] = f1.s;
        }
        rs += __shfl_xor(rs, 32);
        l_s += rs;

        // O^T += V^T · P : A=V^T[dim][key] direct from v_t, B=P[key][q] in regs
        const u16* vb = vt + ((size_t)bh * 128 + ln) * S + kbase;
        __builtin_amdgcn_s_setprio(1);
#pragma unroll
        for (int kt2 = 0; kt2 < 2; kt2++)
#pragma unroll
            for (int s = 0; s < 2; s++)
#pragma unroll
                for (int dt = 0; dt < 4; dt++) {
                    short8 av = *(const short8*)(vb + (size_t)(dt * 32) * S + kt2 * 32 + s * 16 + hi * 8);
                    o[dt] = __builtin_amdgcn_mfma_f32_32x32x16_bf16(av, bp[kt2][s], o[dt], 0, 0, 0);
                }
        __builtin_amdgcn_s_setprio(0);
    }

    // epilogue: C col=q=ln, row=dim=dt*32+(r&3)+8*(r>>2)+4hi -> 4-consecutive-dim packs
    float inv = 1.0f / l_s;
    u16* orow = out + (size_t)(b * S + qrow + ln) * 2048 + h * 128;
#pragma unroll
    for (int dt = 0; dt < 4; dt++)
#pragma unroll
        for (int g = 0; g < 4; g++) {
            ushort4 pk4;
            pk4.x = f2bf(o[dt][g * 4 + 0] * inv);
            pk4.y = f2bf(o[dt][g * 4 + 1] * inv);
            pk4.z = f2bf(o[dt][g * 4 + 2] * inv);
            pk4.w = f2bf(o[dt][g * 4 + 3] * inv);
            *(ushort4*)(orow + dt * 32 + g * 8 + hi * 4) = pk4;
        }
}

extern "C" void kernel_launch(void* const* d_in, const int* in_sizes, int n_in,
                              void* d_out, int out_size, void* d_ws, size_t ws_size,
                              hipStream_t stream) {
    const int B = 2, S = 2048, D = 2048, H = 16;
    const int M = B * S;                       // 4096
    const int NP = 3648;                       // merged proj cols: 2048+1024+512+64
    const int NPpad = 3712;                    // 29 tiles of 128
    // 1/sqrt(192) * log2(e): softmax runs in exp2 domain (folded into Wq/Wq_rope)
    const float scale = 0.07216878364870323f * 1.4426950408889634f;
    const float* x    = (const float*)d_in[0];
    const float* Wq   = (const float*)d_in[1];
    const float* Wqr  = (const float*)d_in[2];
    const float* Wkvd = (const float*)d_in[3];
    const float* Wkvu = (const float*)d_in[4];
    const float* Wkr  = (const float*)d_in[5];
    const float* Wo   = (const float*)d_in[6];

    u16* p = (u16*)d_ws;
    u16* xb     = p; p += (size_t)M * D;             // 16.8 MB
    u16* WprojT = p; p += (size_t)NPpad * 2048;      // rows: [Wq|Wqr|Wkvd|Wkr|pad]
    u16* WkvuT  = p; p += (size_t)4096 * 512;
    u16* WoT    = p; p += (size_t)2048 * 2048;
    u16* proj   = p; p += (size_t)M * NPpad;         // [q_c|q_r|c_kv|k_r] row-major
    u16* kv     = p; p += (size_t)M * 4096;
    u16* v_t    = p; p += (size_t)B * H * 128 * S;
    u16* attn   = p; p += (size_t)M * 2048;

    u16* q_c = proj;                 // cols 0..2047
    u16* q_r = proj + 2048;          // cols 2048..3071
    u16* ckv = proj + 3072;          // cols 3072..3583
    u16* k_r = proj + 3584;          // cols 3584..3647

    // 1) casts / transposes (Wq, Wq_rope pre-scaled by 1/sqrt(192)*log2e)
    cast_f32_bf16<<<(M * D) / 4 / 256, 256, 0, stream>>>(x, xb, M * D);
    transpose_cast<<<dim3(32, 32), 256, 0, stream>>>(Wq,   WprojT,               2048, 2048, scale);
    transpose_cast<<<dim3(32, 16), 256, 0, stream>>>(Wqr,  WprojT + 2048 * 2048, 2048, 1024, scale);
    transpose_cast<<<dim3(32, 8),  256, 0, stream>>>(Wkvd, WprojT + 3072 * 2048, 2048, 512, 1.0f);
    transpose_cast<<<dim3(32, 1),  256, 0, stream>>>(Wkr,  WprojT + 3584 * 2048, 2048, 64, 1.0f);
    transpose_cast<<<dim3(8, 64),  256, 0, stream>>>(Wkvu, WkvuT, 512, 4096, 1.0f);
    transpose_cast<<<dim3(32, 32), 256, 0, stream>>>(Wo,   WoT,   2048, 2048, 1.0f);

    // 2) merged projection GEMM: proj = xb @ WprojT^T  (grid 32x29 = 928 blocks)
    gemm_bt<0, 2048, NP><<<dim3(32, 29), 256, 0, stream>>>(xb, 2048, WprojT, proj, NPpad);

    // 3) RoPE (in place on proj slices; q_r pre-scaled — rotation linear, scale commutes)
    rope_kernel<<<(M * 16 * 32) / 256, 256, 0, stream>>>(q_r, M, 16, S - 1, NPpad);
    rope_kernel<<<(M * 32) / 256, 256, 0, stream>>>(k_r, M, 1, S - 1, NPpad);

    // 4) kv up-projection (A = c_kv inside proj, lda = NPpad), V transpose
    gemm_bt<0, 512, 4096><<<dim3(32, 32), 256, 0, stream>>>(ckv, NPpad, WkvuT, kv, 4096);
    transpose_v<<<dim3(32, 2, 32), 256, 0, stream>>>(kv, v_t, S);

    // 5) attention — grid (bh, 16): cache-direct, zero-LDS, per-wave early exit
    mla_attn<<<dim3(32, 16), 256, 0, stream>>>(q_c, NPpad, q_r, NPpad, kv, k_r, NPpad,
                                               v_t, attn, S);

    // 6) output projection -> fp32 d_out
    gemm_bt<1, 2048, 2048><<<dim3(32, 16), 256, 0, stream>>>(attn, 2048, WoT, d_out, 2048);
}

// Round 6
// 397.363 us; speedup vs baseline: 1.4404x; 1.4404x over previous
//
#include <hip/hip_runtime.h>
#include <hip/hip_bf16.h>
#include <cstdint>
#include <cstddef>

typedef unsigned short u16;
typedef __attribute__((ext_vector_type(8))) short short8;   // 8 bf16 = 4 VGPRs (MFMA A/B frag)
typedef __attribute__((ext_vector_type(4))) float f32x4;    // MFMA C/D frag (16x16)
typedef __attribute__((ext_vector_type(16))) float f32x16;  // MFMA C/D frag (32x32)

__device__ __forceinline__ u16 f2bf(float f) {
    union { float f; uint32_t u; } v; v.f = f;
    uint32_t u = v.u;
    return (u16)((u + 0x7fffu + ((u >> 16) & 1u)) >> 16);   // RNE
}
__device__ __forceinline__ float bf2f(u16 u) {
    union { uint32_t u; float f; } v; v.u = ((uint32_t)u) << 16;
    return v.f;
}
// raw v_exp_f32 (2^x): guaranteed single HW op (args finite, >= -1e30 -> 0)
__device__ __forceinline__ float exp2_hw(float x) {
    float r;
    asm("v_exp_f32 %0, %1" : "=v"(r) : "v"(x));
    return r;
}
// v_cvt_pk_bf16_f32: dword = {bf16(lo) | bf16(hi)<<16}, RNE — 1 op vs 8 for manual pack
__device__ __forceinline__ uint32_t cvtpk(float lo, float hi) {
    uint32_t r;
    asm("v_cvt_pk_bf16_f32 %0, %1, %2" : "=v"(r) : "v"(lo), "v"(hi));
    return r;
}
// v_permlane32_swap_b32 (a,b): a' = [a.lo(0..31) | b.lo as hi], b' = [a.hi as lo | b.hi]
// i.e. swaps a's upper 32 lanes with b's lower 32 lanes. Off the DS pipe (VALU).
__device__ __forceinline__ void permswap(uint32_t& a, uint32_t& b) {
    asm("v_permlane32_swap_b32 %0, %1" : "+v"(a), "+v"(b));
}
// cross-half (lane l <-> l^32) reductions without touching the DS pipe
__device__ __forceinline__ float xhalf_max(float x) {
    union { float f; uint32_t u; } a, b; a.f = x; b.f = x;
    permswap(a.u, b.u);                 // a = x[l&31], b = x[32+(l&31)] on every lane
    return fmaxf(a.f, b.f);
}
__device__ __forceinline__ float xhalf_sum(float x) {
    union { float f; uint32_t u; } a, b; a.f = x; b.f = x;
    permswap(a.u, b.u);
    return a.f + b.f;
}

// async global->LDS 16B copy (m97: global_load_lds_dwordx4).
__device__ __forceinline__ void async_cp16(const u16* g, u16* l) {
    __builtin_amdgcn_global_load_lds(
        (const __attribute__((address_space(1))) unsigned int*)g,
        (__attribute__((address_space(3))) unsigned int*)l, 16, 0, 0);
}

// ---------------- cast fp32 -> bf16 (vectorized) ----------------
__global__ __launch_bounds__(256) void cast_f32_bf16(const float* __restrict__ in,
                                                     u16* __restrict__ out, int n) {
    int i = (blockIdx.x * 256 + threadIdx.x) * 4;
    if (i >= n) return;
    float4 v = *(const float4*)(in + i);
    ushort4 r;
    r.x = f2bf(v.x); r.y = f2bf(v.y); r.z = f2bf(v.z); r.w = f2bf(v.w);
    *(ushort4*)(out + i) = r;
}

// ---------------- W (K,N) fp32 -> Wt (N,K) bf16 (optionally pre-scaled) ----------------
__global__ __launch_bounds__(256) void transpose_cast(const float* __restrict__ W,
                                                      u16* __restrict__ Wt, int K, int N,
                                                      float smul) {
    __shared__ u16 tile[64][72];
    int kt = blockIdx.x * 64, nt = blockIdx.y * 64;
    int t = threadIdx.x;
#pragma unroll
    for (int i = 0; i < 16; i++) {
        int idx = t + i * 256; int kl = idx >> 6, nl = idx & 63;
        tile[kl][nl] = f2bf(W[(size_t)(kt + kl) * N + nt + nl] * smul);
    }
    __syncthreads();
#pragma unroll
    for (int i = 0; i < 16; i++) {
        int idx = t + i * 256; int nl = idx >> 6, kl = idx & 63;
        Wt[(size_t)(nt + nl) * K + kt + kl] = tile[kl][nl];
    }
}

// ---------------- bf16 GEMM (m97 structure), compile-time shapes ----------------
template <int OUTF32, int KDIM, int NDIM>
__global__ __launch_bounds__(256) void gemm_bt(const u16* __restrict__ A, int lda,
                                               const u16* __restrict__ Bt,
                                               void* __restrict__ Cout, int ldc) {
    __shared__ __align__(16) u16 Al[128 * 32];
    __shared__ __align__(16) u16 Bl[128 * 32];
    int m0 = blockIdx.x * 128, n0 = blockIdx.y * 128;
    int t = threadIdx.x;
    int w = t >> 6, l = t & 63;
    int lm = l & 15, lq = l >> 4;
    int wm = (w >> 1) * 64, wn = (w & 1) * 64;
    f32x4 acc[4][4] = {};

    for (int k0 = 0; k0 < KDIM; k0 += 32) {
#pragma unroll
        for (int c = 0; c < 2; c++) {
            int chunk = w * 128 + c * 64 + l;
            int row = chunk >> 2, col8 = (chunk & 3) * 8;
            async_cp16(A + (size_t)(m0 + row) * lda + k0 + col8,
                       Al + (w * 128 + c * 64) * 8);
            int brow = n0 + row;
            if (NDIM % 128 != 0) { if (brow >= NDIM) brow = NDIM - 1; }
            async_cp16(Bt + (size_t)brow * KDIM + k0 + col8,
                       Bl + (w * 128 + c * 64) * 8);
        }
        __syncthreads();
        short8 af[4], bfr[4];
#pragma unroll
        for (int mt = 0; mt < 4; mt++)
            af[mt] = *(const short8*)(Al + (wm + mt * 16 + lm) * 32 + lq * 8);
#pragma unroll
        for (int nt = 0; nt < 4; nt++)
            bfr[nt] = *(const short8*)(Bl + (wn + nt * 16 + lm) * 32 + lq * 8);
#pragma unroll
        for (int mt = 0; mt < 4; mt++)
#pragma unroll
            for (int nt = 0; nt < 4; nt++)
                acc[mt][nt] = __builtin_amdgcn_mfma_f32_16x16x32_bf16(af[mt], bfr[nt], acc[mt][nt], 0, 0, 0);
        __syncthreads();
    }
#pragma unroll
    for (int mt = 0; mt < 4; mt++) {
#pragma unroll
        for (int nt = 0; nt < 4; nt++) {
            int col = n0 + wn + nt * 16 + lm;
            if (col < NDIM) {
#pragma unroll
                for (int r = 0; r < 4; r++) {
                    int row = m0 + wm + mt * 16 + lq * 4 + r;
                    if (OUTF32) ((float*)Cout)[(size_t)row * ldc + col] = acc[mt][nt][r];
                    else        ((u16*)Cout)[(size_t)row * ldc + col] = f2bf(acc[mt][nt][r]);
                }
            }
        }
    }
}

// ---------------- RoPE in-place on (rows, nheads*64) bf16, row stride `stride` ----------------
__global__ __launch_bounds__(256) void rope_kernel(u16* __restrict__ x, int rows,
                                                   int nheads, int Smask, int stride) {
    int i = blockIdx.x * 256 + threadIdx.x;
    int total = rows * nheads * 32;
    if (i >= total) return;
    int j = i & 31;
    int h = (i >> 5) % nheads;
    int row = i / (32 * nheads);
    int pos = row & Smask;
    float f = exp2f((float)j * -0.4152410118609828f);
    float ang = (float)pos * f;
    float c = cosf(ang), s = sinf(ang);
    u16* p = x + (size_t)row * stride + h * 64 + j;
    float x1 = bf2f(p[0]), x2 = bf2f(p[32]);
    p[0]  = f2bf(x1 * c - x2 * s);
    p[32] = f2bf(x2 * c + x1 * s);
}

// ---------------- V slice of kv -> v_t (B,H,128,S) bf16 ----------------
__global__ __launch_bounds__(256) void transpose_v(const u16* __restrict__ kv,
                                                   u16* __restrict__ vt, int S) {
    __shared__ u16 tile[64][72];
    int bh = blockIdx.z; int b = bh >> 4, h = bh & 15;
    int s0 = blockIdx.x * 64, d0 = blockIdx.y * 64;
    int t = threadIdx.x;
#pragma unroll
    for (int i = 0; i < 16; i++) {
        int idx = t + i * 256; int sl = idx >> 6, dl = idx & 63;
        tile[sl][dl] = kv[(size_t)(b * S + s0 + sl) * 4096 + 2048 + h * 128 + d0 + dl];
    }
    __syncthreads();
#pragma unroll
    for (int i = 0; i < 16; i++) {
        int idx = t + i * 256; int dl = idx >> 6, sl = idx & 63;
        vt[((size_t)(bh * 128 + d0 + dl)) * S + s0 + sl] = tile[sl][dl];
    }
}

// ---------------- Flash MLA attention v10 = v7 + in-register P via permlane ----------------
// Round-5 post-mortem: v9's cache-direct loads were 64-line scatters (A-frag row stride
// 8KB/4KB) at L2 latency with 2 waves/SIMD -> 252us. LDS staging is layout-fixing, not
// bandwidth-saving: keep v7's structure (98.8us, proven).
// v10 micro-opts (v6's pieces, exonerated: v6's NaN was the -INF defer-max trap on fully-
// masked diagonal half-lanes, fixed in v7 by finite NEG; layouts validated by v7's pass):
//  * P-pack: v_cvt_pk_bf16_f32 (1 op vs 8) + v_permlane32_swap (VALU) — removes
//    16 ds_bpermute + 32 selects per tile. permswap(c0,c2);permswap(c1,c3) is
//    element-identical to v7's proven hi?shfl:own selects.
//  * cross-half max/sum via permlane (2 more DS ops removed), exp via raw v_exp_f32.
__global__ __launch_bounds__(256, 2) void mla_attn(const u16* __restrict__ qc, int qcs,
                                                   const u16* __restrict__ qr, int qrs,
                                                   const u16* __restrict__ kvbuf,
                                                   const u16* __restrict__ kr, int krs,
                                                   const u16* __restrict__ vt,
                                                   u16* __restrict__ out, int S) {
    __shared__ __align__(16) u16 Kl[64 * 200];       // 64 keys x 192 dims, stride 200
    __shared__ __align__(16) u16 Vl[128 * 72];       // 128 dims x 64 keys, stride 72
    const float NEG = -1e30f;
    int bh = blockIdx.x; int b = bh >> 4, h = bh & 15;   // XCD-pinning: XCD = bh%8
    int y = blockIdx.y;
    int qt = (y < 8) ? (15 - y) : (y - 8);
    int t = threadIdx.x, w = t >> 6, l = t & 63;
    int ln = l & 31, hi = l >> 5;

    short8 kreg[6], vreg[4];
    auto load_tile = [&](int kbase) {
#pragma unroll
        for (int c = 0; c < 6; c++) {                 // K: 64 rows x 24 chunks(16B)
            int idx = t + c * 256;
            int row = idx / 24, col = (idx % 24) * 8;
            const u16* src = (col < 128)
                ? kvbuf + (size_t)(b * S + kbase + row) * 4096 + h * 128 + col
                : kr + (size_t)(b * S + kbase + row) * krs + (col - 128);
            kreg[c] = *(const short8*)src;
        }
#pragma unroll
        for (int c = 0; c < 4; c++) {                 // V^T: 128 rows x 8 chunks(16B)
            int idx = t + c * 256;
            int row = idx >> 3, col = (idx & 7) * 8;
            vreg[c] = *(const short8*)(vt + ((size_t)bh * 128 + row) * S + kbase + col);
        }
    };

    int qrow = qt * 128 + w * 32;                     // this wave's 32 q-rows
    int ntiles = 2 * qt + 2;

    // Q B-frags for 32x32x16: lane holds col q=ln, k = ks*16 + hi*8 + j (pre-scaled)
    short8 bq[12];
    {
        const u16* qc_row = qc + (size_t)(b * S + qrow + ln) * qcs + h * 128;
#pragma unroll
        for (int ks = 0; ks < 8; ks++) bq[ks] = *(const short8*)(qc_row + ks * 16 + hi * 8);
        const u16* qr_row = qr + (size_t)(b * S + qrow + ln) * qrs + h * 64;
#pragma unroll
        for (int ks = 0; ks < 4; ks++) bq[8 + ks] = *(const short8*)(qr_row + ks * 16 + hi * 8);
    }

    f32x16 o[4] = {};                             // O^T: 4 dim-tiles x (32x32 C)
    float m_s = 0.0f, l_s = 0.f;                  // running max (ref 0) / denom

    load_tile(0);
    for (int kt = 0; kt < ntiles; kt++) {
        int kbase = kt * 64;
        __syncthreads();                          // prior iter's LDS reads done
#pragma unroll
        for (int c = 0; c < 6; c++) {
            int idx = t + c * 256;
            int row = idx / 24, col = (idx % 24) * 8;
            *(short8*)(Kl + row * 200 + col) = kreg[c];
        }
#pragma unroll
        for (int c = 0; c < 4; c++) {
            int idx = t + c * 256;
            int row = idx >> 3, col = (idx & 7) * 8;
            *(short8*)(Vl + row * 72 + col) = vreg[c];
        }
        __syncthreads();                          // staging visible to all waves
        if (kt + 1 < ntiles) load_tile(kbase + 64);   // overlaps compute below

        if (kbase > qrow + 31) continue;          // fully-masked for this wave

        // S^T: sacc[kt2][r] = S_log2[key=kbase+kt2*32+(r&3)+8(r>>2)+4hi][q=qrow+ln]
        f32x16 sacc[2] = {};
        __builtin_amdgcn_s_setprio(1);
#pragma unroll
        for (int ks = 0; ks < 12; ks++) {
            short8 ak0 = *(const short8*)(Kl + ln * 200 + ks * 16 + hi * 8);
            short8 ak1 = *(const short8*)(Kl + (32 + ln) * 200 + ks * 16 + hi * 8);
            sacc[0] = __builtin_amdgcn_mfma_f32_32x32x16_bf16(ak0, bq[ks], sacc[0], 0, 0, 0);
            sacc[1] = __builtin_amdgcn_mfma_f32_32x32x16_bf16(ak1, bq[ks], sacc[1], 0, 0, 0);
        }
        __builtin_amdgcn_s_setprio(0);

        if (kbase + 63 > qrow) {                  // diagonal tiles: causal mask (finite)
            int qi = qrow + ln;
#pragma unroll
            for (int kt2 = 0; kt2 < 2; kt2++)
#pragma unroll
                for (int r = 0; r < 16; r++) {
                    int key = kbase + kt2 * 32 + (r & 3) + 8 * (r >> 2) + 4 * hi;
                    if (key > qi) sacc[kt2][r] = NEG;
                }
        }

        // online softmax (log2 domain, ref max 0), lane pair (l, l^32) shares q-row
        float m01 = NEG, m23 = NEG;               // balanced tree (better ILP)
#pragma unroll
        for (int r = 0; r < 16; r += 2) {
            m01 = fmaxf(m01, fmaxf(sacc[0][r], sacc[0][r + 1]));
            m23 = fmaxf(m23, fmaxf(sacc[1][r], sacc[1][r + 1]));
        }
        float mx = xhalf_max(fmaxf(m01, m23));
        if (!__all(mx - m_s <= 8.0f)) {           // defer-max (T13): P <= 2^8 otherwise
            float mnew = fmaxf(m_s, mx);
            float alpha = exp2_hw(m_s - mnew);
            m_s = mnew;
            l_s *= alpha;
#pragma unroll
            for (int dt = 0; dt < 4; dt++) o[dt] *= alpha;
        }

        // P = 2^(S-m): exp + cvt_pk + permlane32_swap -> bf16 B-frags fully in-register
        float rs = 0.f;
        short8 bp[2][2];
#pragma unroll
        for (int kt2 = 0; kt2 < 2; kt2++) {
            float p[16];
#pragma unroll
            for (int r = 0; r < 16; r++) p[r] = exp2_hw(sacc[kt2][r] - m_s);
#pragma unroll
            for (int r = 0; r < 16; r += 4)
                rs += (p[r] + p[r + 1]) + (p[r + 2] + p[r + 3]);
            // own regs hold keys 4hi+{0..3}, 8+4hi+{0..3}, 16+.., 24+.. (rel. kt2*32)
            uint32_t c0 = cvtpk(p[0], p[1]),  c1 = cvtpk(p[2], p[3]);
            uint32_t c2 = cvtpk(p[4], p[5]),  c3 = cvtpk(p[6], p[7]);
            permswap(c0, c2); permswap(c1, c3);   // == v7's hi?shfl:own selects
            union { uint32_t u[4]; short8 s; } f0 = {{c0, c1, c2, c3}};
            bp[kt2][0] = f0.s;
            uint32_t c4 = cvtpk(p[8], p[9]),   c5 = cvtpk(p[10], p[11]);
            uint32_t c6 = cvtpk(p[12], p[13]), c7 = cvtpk(p[14], p[15]);
            permswap(c4, c6); permswap(c5, c7);
            union { uint32_t u[4]; short8 s; } f1 = {{c4, c5, c6, c7}};
            bp[kt2][1] = f1.s;
        }
        l_s += xhalf_sum(rs);

        // O^T += V^T · P : A=V^T[dim][key] from LDS, B=P[key][q] in regs
        __builtin_amdgcn_s_setprio(1);
#pragma unroll
        for (int kt2 = 0; kt2 < 2; kt2++)
#pragma unroll
            for (int s = 0; s < 2; s++)
#pragma unroll
                for (int dt = 0; dt < 4; dt++) {
                    short8 av = *(const short8*)(Vl + (dt * 32 + ln) * 72 + kt2 * 32 + s * 16 + hi * 8);
                    o[dt] = __builtin_amdgcn_mfma_f32_32x32x16_bf16(av, bp[kt2][s], o[dt], 0, 0, 0);
                }
        __builtin_amdgcn_s_setprio(0);
    }

    // epilogue: C col=q=ln, row=dim=dt*32+(r&3)+8*(r>>2)+4hi -> 4-consecutive-dim packs
    float inv = 1.0f / l_s;
    u16* orow = out + (size_t)(b * S + qrow + ln) * 2048 + h * 128;
#pragma unroll
    for (int dt = 0; dt < 4; dt++)
#pragma unroll
        for (int g = 0; g < 4; g++) {
            ushort4 pk4;
            pk4.x = f2bf(o[dt][g * 4 + 0] * inv);
            pk4.y = f2bf(o[dt][g * 4 + 1] * inv);
            pk4.z = f2bf(o[dt][g * 4 + 2] * inv);
            pk4.w = f2bf(o[dt][g * 4 + 3] * inv);
            *(ushort4*)(orow + dt * 32 + g * 8 + hi * 4) = pk4;
        }
}

extern "C" void kernel_launch(void* const* d_in, const int* in_sizes, int n_in,
                              void* d_out, int out_size, void* d_ws, size_t ws_size,
                              hipStream_t stream) {
    const int B = 2, S = 2048, D = 2048, H = 16;
    const int M = B * S;                       // 4096
    const int NP = 3648;                       // merged proj cols: 2048+1024+512+64
    const int NPpad = 3712;                    // 29 tiles of 128
    // 1/sqrt(192) * log2(e): softmax runs in exp2 domain (folded into Wq/Wq_rope)
    const float scale = 0.07216878364870323f * 1.4426950408889634f;
    const float* x    = (const float*)d_in[0];
    const float* Wq   = (const float*)d_in[1];
    const float* Wqr  = (const float*)d_in[2];
    const float* Wkvd = (const float*)d_in[3];
    const float* Wkvu = (const float*)d_in[4];
    const float* Wkr  = (const float*)d_in[5];
    const float* Wo   = (const float*)d_in[6];

    u16* p = (u16*)d_ws;
    u16* xb     = p; p += (size_t)M * D;             // 16.8 MB
    u16* WprojT = p; p += (size_t)NPpad * 2048;      // rows: [Wq|Wqr|Wkvd|Wkr|pad]
    u16* WkvuT  = p; p += (size_t)4096 * 512;
    u16* WoT    = p; p += (size_t)2048 * 2048;
    u16* proj   = p; p += (size_t)M * NPpad;         // [q_c|q_r|c_kv|k_r] row-major
    u16* kv     = p; p += (size_t)M * 4096;
    u16* v_t    = p; p += (size_t)B * H * 128 * S;
    u16* attn   = p; p += (size_t)M * 2048;

    u16* q_c = proj;                 // cols 0..2047
    u16* q_r = proj + 2048;          // cols 2048..3071
    u16* ckv = proj + 3072;          // cols 3072..3583
    u16* k_r = proj + 3584;          // cols 3584..3647

    // 1) casts / transposes (Wq, Wq_rope pre-scaled by 1/sqrt(192)*log2e)
    cast_f32_bf16<<<(M * D) / 4 / 256, 256, 0, stream>>>(x, xb, M * D);
    transpose_cast<<<dim3(32, 32), 256, 0, stream>>>(Wq,   WprojT,               2048, 2048, scale);
    transpose_cast<<<dim3(32, 16), 256, 0, stream>>>(Wqr,  WprojT + 2048 * 2048, 2048, 1024, scale);
    transpose_cast<<<dim3(32, 8),  256, 0, stream>>>(Wkvd, WprojT + 3072 * 2048, 2048, 512, 1.0f);
    transpose_cast<<<dim3(32, 1),  256, 0, stream>>>(Wkr,  WprojT + 3584 * 2048, 2048, 64, 1.0f);
    transpose_cast<<<dim3(8, 64),  256, 0, stream>>>(Wkvu, WkvuT, 512, 4096, 1.0f);
    transpose_cast<<<dim3(32, 32), 256, 0, stream>>>(Wo,   WoT,   2048, 2048, 1.0f);

    // 2) merged projection GEMM: proj = xb @ WprojT^T  (grid 32x29 = 928 blocks)
    gemm_bt<0, 2048, NP><<<dim3(32, 29), 256, 0, stream>>>(xb, 2048, WprojT, proj, NPpad);

    // 3) RoPE (in place on proj slices; q_r pre-scaled — rotation linear, scale commutes)
    rope_kernel<<<(M * 16 * 32) / 256, 256, 0, stream>>>(q_r, M, 16, S - 1, NPpad);
    rope_kernel<<<(M * 32) / 256, 256, 0, stream>>>(k_r, M, 1, S - 1, NPpad);

    // 4) kv up-projection (A = c_kv inside proj, lda = NPpad), V transpose
    gemm_bt<0, 512, 4096><<<dim3(32, 32), 256, 0, stream>>>(ckv, NPpad, WkvuT, kv, 4096);
    transpose_v<<<dim3(32, 2, 32), 256, 0, stream>>>(kv, v_t, S);

    // 5) attention — grid (bh, 16 q-tiles of 128): pair-balanced, XCD/CU-pinned
    mla_attn<<<dim3(32, 16), 256, 0, stream>>>(q_c, NPpad, q_r, NPpad, kv, k_r, NPpad,
                                               v_t, attn, S);

    // 6) output projection -> fp32 d_out
    gemm_bt<1, 2048, 2048><<<dim3(32, 16), 256, 0, stream>>>(attn, 2048, WoT, d_out, 2048);
}

// Round 7
// 384.376 us; speedup vs baseline: 1.4891x; 1.0338x over previous
//
#include <hip/hip_runtime.h>
#include <hip/hip_bf16.h>
#include <cstdint>
#include <cstddef>

typedef unsigned short u16;
typedef __attribute__((ext_vector_type(8))) short short8;   // 8 bf16 = 4 VGPRs (MFMA A/B frag)
typedef __attribute__((ext_vector_type(4))) float f32x4;    // MFMA C/D frag (16x16)
typedef __attribute__((ext_vector_type(16))) float f32x16;  // MFMA C/D frag (32x32)

__device__ __forceinline__ u16 f2bf(float f) {
    union { float f; uint32_t u; } v; v.f = f;
    uint32_t u = v.u;
    return (u16)((u + 0x7fffu + ((u >> 16) & 1u)) >> 16);   // RNE
}
__device__ __forceinline__ float bf2f(u16 u) {
    union { uint32_t u; float f; } v; v.u = ((uint32_t)u) << 16;
    return v.f;
}
// raw v_exp_f32 (2^x): single HW op (args finite, large-neg -> 0)
__device__ __forceinline__ float exp2_hw(float x) {
    float r;
    asm("v_exp_f32 %0, %1" : "=v"(r) : "v"(x));
    return r;
}
// v_cvt_pk_bf16_f32: dword = {bf16(lo) | bf16(hi)<<16}, RNE
__device__ __forceinline__ uint32_t cvtpk(float lo, float hi) {
    uint32_t r;
    asm("v_cvt_pk_bf16_f32 %0, %1, %2" : "=v"(r) : "v"(lo), "v"(hi));
    return r;
}
// v_permlane32_swap_b32: swaps a's upper-32-lane halves with b's lower-32-lane halves
__device__ __forceinline__ void permswap(uint32_t& a, uint32_t& b) {
    asm("v_permlane32_swap_b32 %0, %1" : "+v"(a), "+v"(b));
}
__device__ __forceinline__ float xhalf_max(float x) {
    union { float f; uint32_t u; } a, b; a.f = x; b.f = x;
    permswap(a.u, b.u);
    return fmaxf(a.f, b.f);
}
__device__ __forceinline__ float xhalf_sum(float x) {
    union { float f; uint32_t u; } a, b; a.f = x; b.f = x;
    permswap(a.u, b.u);
    return a.f + b.f;
}

// async global->LDS 16B copy (global_load_lds_dwordx4). LDS dest = wave-uniform base.
__device__ __forceinline__ void async_cp16(const u16* g, u16* l) {
    __builtin_amdgcn_global_load_lds(
        (const __attribute__((address_space(1))) unsigned int*)g,
        (__attribute__((address_space(3))) unsigned int*)l, 16, 0, 0);
}

// ---------------- cast fp32 -> bf16 (vectorized) ----------------
__global__ __launch_bounds__(256) void cast_f32_bf16(const float* __restrict__ in,
                                                     u16* __restrict__ out, int n) {
    int i = (blockIdx.x * 256 + threadIdx.x) * 4;
    if (i >= n) return;
    float4 v = *(const float4*)(in + i);
    ushort4 r;
    r.x = f2bf(v.x); r.y = f2bf(v.y); r.z = f2bf(v.z); r.w = f2bf(v.w);
    *(ushort4*)(out + i) = r;
}

// ---------------- W (K,N) fp32 -> Wt (N,K) bf16 (optionally pre-scaled) ----------------
__global__ __launch_bounds__(256) void transpose_cast(const float* __restrict__ W,
                                                      u16* __restrict__ Wt, int K, int N,
                                                      float smul) {
    __shared__ u16 tile[64][72];
    int kt = blockIdx.x * 64, nt = blockIdx.y * 64;
    int t = threadIdx.x;
#pragma unroll
    for (int i = 0; i < 16; i++) {
        int idx = t + i * 256; int kl = idx >> 6, nl = idx & 63;
        tile[kl][nl] = f2bf(W[(size_t)(kt + kl) * N + nt + nl] * smul);
    }
    __syncthreads();
#pragma unroll
    for (int i = 0; i < 16; i++) {
        int idx = t + i * 256; int nl = idx >> 6, kl = idx & 63;
        Wt[(size_t)(nt + nl) * K + kt + kl] = tile[kl][nl];
    }
}

// ---------------- bf16 GEMM (m97 structure) — kept for the Wo projection ----------------
template <int OUTF32, int KDIM, int NDIM>
__global__ __launch_bounds__(256) void gemm_bt(const u16* __restrict__ A, int lda,
                                               const u16* __restrict__ Bt,
                                               void* __restrict__ Cout, int ldc) {
    __shared__ __align__(16) u16 Al[128 * 32];
    __shared__ __align__(16) u16 Bl[128 * 32];
    int m0 = blockIdx.x * 128, n0 = blockIdx.y * 128;
    int t = threadIdx.x;
    int w = t >> 6, l = t & 63;
    int lm = l & 15, lq = l >> 4;
    int wm = (w >> 1) * 64, wn = (w & 1) * 64;
    f32x4 acc[4][4] = {};

    for (int k0 = 0; k0 < KDIM; k0 += 32) {
#pragma unroll
        for (int c = 0; c < 2; c++) {
            int chunk = w * 128 + c * 64 + l;
            int row = chunk >> 2, col8 = (chunk & 3) * 8;
            async_cp16(A + (size_t)(m0 + row) * lda + k0 + col8,
                       Al + (w * 128 + c * 64) * 8);
            int brow = n0 + row;
            if (NDIM % 128 != 0) { if (brow >= NDIM) brow = NDIM - 1; }
            async_cp16(Bt + (size_t)brow * KDIM + k0 + col8,
                       Bl + (w * 128 + c * 64) * 8);
        }
        __syncthreads();
        short8 af[4], bfr[4];
#pragma unroll
        for (int mt = 0; mt < 4; mt++)
            af[mt] = *(const short8*)(Al + (wm + mt * 16 + lm) * 32 + lq * 8);
#pragma unroll
        for (int nt = 0; nt < 4; nt++)
            bfr[nt] = *(const short8*)(Bl + (wn + nt * 16 + lm) * 32 + lq * 8);
#pragma unroll
        for (int mt = 0; mt < 4; mt++)
#pragma unroll
            for (int nt = 0; nt < 4; nt++)
                acc[mt][nt] = __builtin_amdgcn_mfma_f32_16x16x32_bf16(af[mt], bfr[nt], acc[mt][nt], 0, 0, 0);
        __syncthreads();
    }
#pragma unroll
    for (int mt = 0; mt < 4; mt++) {
#pragma unroll
        for (int nt = 0; nt < 4; nt++) {
            int col = n0 + wn + nt * 16 + lm;
            if (col < NDIM) {
#pragma unroll
                for (int r = 0; r < 4; r++) {
                    int row = m0 + wm + mt * 16 + lq * 4 + r;
                    if (OUTF32) ((float*)Cout)[(size_t)row * ldc + col] = acc[mt][nt][r];
                    else        ((u16*)Cout)[(size_t)row * ldc + col] = f2bf(acc[mt][nt][r]);
                }
            }
        }
    }
}

// ---------------- 256x256 bf16 GEMM: BK=32, 4-deep LDS ring, counted vmcnt ----------------
// Round-6: proj GEMM (m97 structure) = 642 TF, MfmaUtil 25%, 7.6e6 bank conflicts.
// Port of the counted-vmcnt 256^2 template (guide §5 / m201 family):
//  * 512 thr = 8 waves (2M x 4N); wave tile 128x64; acc 8x4 f32x4 (128 VGPR).
//  * BK=32, 4 LDS buffers (4 x 32KB = 128KB ring): stage K-step j+2 while computing j.
//    Loads stay in flight ACROSS barriers: s_waitcnt vmcnt(4) + raw s_barrier once per
//    K-step; vmcnt(0) only at the tail (T4 lever: counted-vs-drain +38-73%, m218).
//  * T2 swizzle: read slot = lq ^ ((lm>>1)&3); staging pre-swizzles the GLOBAL source
//    col by the same involution (both-sides-or-neither, rule #21). Breaks the 8-way
//    b128 conflict of 64B-stride rows down to 2-way (free).
//  * T5 setprio around the 32-MFMA cluster.
// Correctness ledger: ring distance 2 — iter j writes buf (j+2)&3, reads buf j&3; buf
// (j+2)&3 was last read in iter j-2, sealed 2 barriers earlier (no WAR). vmcnt counts
// 4 loads/thread/K-step: prologue 8-out wait-4; steady 8-out wait-4; ks=nk-2 wait-0.
template <int KDIM>
__global__ __launch_bounds__(512, 2) void gemm256(const u16* __restrict__ A, int lda,
                                                  const u16* __restrict__ Bt,
                                                  u16* __restrict__ C, int ldc) {
    __shared__ __align__(16) u16 Ab[4][256 * 32];    // 64 KB
    __shared__ __align__(16) u16 Bb[4][256 * 32];    // 64 KB
    const int nk = KDIM / 32;
    int m0 = blockIdx.x * 256, n0 = blockIdx.y * 256;
    int t = threadIdx.x, w = t >> 6, l = t & 63;
    int lm = l & 15, lq = l >> 4;
    int wm = (w >> 2) * 128, wn = (w & 3) * 64;

    // staging: 1024 16B-chunks per 256x32 half (A or B); 512 thr x 2 chunks.
    // chunk c: row = c>>2, slot = c&3; source col pre-swizzled: slot ^ ((row>>1)&3).
    int c1 = t + 512;
    int ar0 = t >> 2,  as0 = (((t >> 0) & 3) ^ ((ar0 >> 1) & 3)) * 8;
    int ar1 = c1 >> 2, as1 = ((c1 & 3) ^ ((ar1 >> 1) & 3)) * 8;
    const u16* Ap0 = A + (size_t)(m0 + ar0) * lda + as0;
    const u16* Ap1 = A + (size_t)(m0 + ar1) * lda + as1;
    const u16* Bp0 = Bt + (size_t)(n0 + ar0) * KDIM + as0;
    const u16* Bp1 = Bt + (size_t)(n0 + ar1) * KDIM + as1;
    int dst0 = (w * 64) * 8;                         // wave-uniform LDS bases (elems)
    int dst1 = (w * 64 + 512) * 8;

    auto stage = [&](int ks) {
        int buf = ks & 3, ko = ks * 32;
        async_cp16(Ap0 + ko, Ab[buf] + dst0);
        async_cp16(Ap1 + ko, Ab[buf] + dst1);
        async_cp16(Bp0 + ko, Bb[buf] + dst0);
        async_cp16(Bp1 + ko, Bb[buf] + dst1);
    };

    // read-side swizzle: row = base16 + lm -> (row>>1)&3 == (lm>>1)&3 (bases are x16)
    int slot = (lq ^ ((lm >> 1) & 3)) * 8;

    f32x4 acc[8][4] = {};
    stage(0); stage(1);
    asm volatile("s_waitcnt vmcnt(4)" ::: "memory");
    __builtin_amdgcn_s_barrier();

    for (int ks = 0; ks < nk; ks++) {
        if (ks + 2 < nk) stage(ks + 2);
        const u16* Al = Ab[ks & 3];
        const u16* Bl = Bb[ks & 3];
        short8 bfr[4], af[8];
#pragma unroll
        for (int nt = 0; nt < 4; nt++)
            bfr[nt] = *(const short8*)(Bl + (wn + nt * 16 + lm) * 32 + slot);
#pragma unroll
        for (int mt = 0; mt < 8; mt++)
            af[mt] = *(const short8*)(Al + (wm + mt * 16 + lm) * 32 + slot);
        __builtin_amdgcn_s_setprio(1);
#pragma unroll
        for (int mt = 0; mt < 8; mt++)
#pragma unroll
            for (int nt = 0; nt < 4; nt++)
                acc[mt][nt] = __builtin_amdgcn_mfma_f32_16x16x32_bf16(af[mt], bfr[nt], acc[mt][nt], 0, 0, 0);
        __builtin_amdgcn_s_setprio(0);
        if (ks + 2 < nk)      { asm volatile("s_waitcnt vmcnt(4)" ::: "memory"); }
        else if (ks + 1 < nk) { asm volatile("s_waitcnt vmcnt(0)" ::: "memory"); }
        if (ks + 1 < nk) __builtin_amdgcn_s_barrier();
    }

#pragma unroll
    for (int mt = 0; mt < 8; mt++)
#pragma unroll
        for (int nt = 0; nt < 4; nt++) {
            int col = n0 + wn + nt * 16 + lm;
            u16* cp = C + (size_t)(m0 + wm + mt * 16 + lq * 4) * ldc + col;
#pragma unroll
            for (int r = 0; r < 4; r++)
                cp[(size_t)r * ldc] = f2bf(acc[mt][nt][r]);
        }
}

// ---------------- RoPE in-place on (rows, nheads*64) bf16, row stride `stride` ----------------
__global__ __launch_bounds__(256) void rope_kernel(u16* __restrict__ x, int rows,
                                                   int nheads, int Smask, int stride) {
    int i = blockIdx.x * 256 + threadIdx.x;
    int total = rows * nheads * 32;
    if (i >= total) return;
    int j = i & 31;
    int h = (i >> 5) % nheads;
    int row = i / (32 * nheads);
    int pos = row & Smask;
    float f = exp2f((float)j * -0.4152410118609828f);
    float ang = (float)pos * f;
    float c = cosf(ang), s = sinf(ang);
    u16* p = x + (size_t)row * stride + h * 64 + j;
    float x1 = bf2f(p[0]), x2 = bf2f(p[32]);
    p[0]  = f2bf(x1 * c - x2 * s);
    p[32] = f2bf(x2 * c + x1 * s);
}

// ---------------- V slice of kv -> v_t (B,H,128,S) bf16 ----------------
__global__ __launch_bounds__(256) void transpose_v(const u16* __restrict__ kv,
                                                   u16* __restrict__ vt, int S) {
    __shared__ u16 tile[64][72];
    int bh = blockIdx.z; int b = bh >> 4, h = bh & 15;
    int s0 = blockIdx.x * 64, d0 = blockIdx.y * 64;
    int t = threadIdx.x;
#pragma unroll
    for (int i = 0; i < 16; i++) {
        int idx = t + i * 256; int sl = idx >> 6, dl = idx & 63;
        tile[sl][dl] = kv[(size_t)(b * S + s0 + sl) * 4096 + 2048 + h * 128 + d0 + dl];
    }
    __syncthreads();
#pragma unroll
    for (int i = 0; i < 16; i++) {
        int idx = t + i * 256; int dl = idx >> 6, sl = idx & 63;
        vt[((size_t)(bh * 128 + d0 + dl)) * S + s0 + sl] = tile[sl][dl];
    }
}

// ---------------- Flash MLA attention v10 (best: ~90us) ----------------
// 32x32 MFMA, 32 q-rows/wave, K/V staged in LDS, P fully in-register via
// cvt_pk + permlane32_swap; defer-max; exp2-domain softmax.
__global__ __launch_bounds__(256, 2) void mla_attn(const u16* __restrict__ qc, int qcs,
                                                   const u16* __restrict__ qr, int qrs,
                                                   const u16* __restrict__ kvbuf,
                                                   const u16* __restrict__ kr, int krs,
                                                   const u16* __restrict__ vt,
                                                   u16* __restrict__ out, int S) {
    __shared__ __align__(16) u16 Kl[64 * 200];       // 64 keys x 192 dims, stride 200
    __shared__ __align__(16) u16 Vl[128 * 72];       // 128 dims x 64 keys, stride 72
    const float NEG = -1e30f;
    int bh = blockIdx.x; int b = bh >> 4, h = bh & 15;   // XCD-pinning: XCD = bh%8
    int y = blockIdx.y;
    int qt = (y < 8) ? (15 - y) : (y - 8);
    int t = threadIdx.x, w = t >> 6, l = t & 63;
    int ln = l & 31, hi = l >> 5;

    short8 kreg[6], vreg[4];
    auto load_tile = [&](int kbase) {
#pragma unroll
        for (int c = 0; c < 6; c++) {                 // K: 64 rows x 24 chunks(16B)
            int idx = t + c * 256;
            int row = idx / 24, col = (idx % 24) * 8;
            const u16* src = (col < 128)
                ? kvbuf + (size_t)(b * S + kbase + row) * 4096 + h * 128 + col
                : kr + (size_t)(b * S + kbase + row) * krs + (col - 128);
            kreg[c] = *(const short8*)src;
        }
#pragma unroll
        for (int c = 0; c < 4; c++) {                 // V^T: 128 rows x 8 chunks(16B)
            int idx = t + c * 256;
            int row = idx >> 3, col = (idx & 7) * 8;
            vreg[c] = *(const short8*)(vt + ((size_t)bh * 128 + row) * S + kbase + col);
        }
    };

    int qrow = qt * 128 + w * 32;                     // this wave's 32 q-rows
    int ntiles = 2 * qt + 2;

    // Q B-frags for 32x32x16: lane holds col q=ln, k = ks*16 + hi*8 + j (pre-scaled)
    short8 bq[12];
    {
        const u16* qc_row = qc + (size_t)(b * S + qrow + ln) * qcs + h * 128;
#pragma unroll
        for (int ks = 0; ks < 8; ks++) bq[ks] = *(const short8*)(qc_row + ks * 16 + hi * 8);
        const u16* qr_row = qr + (size_t)(b * S + qrow + ln) * qrs + h * 64;
#pragma unroll
        for (int ks = 0; ks < 4; ks++) bq[8 + ks] = *(const short8*)(qr_row + ks * 16 + hi * 8);
    }

    f32x16 o[4] = {};                             // O^T: 4 dim-tiles x (32x32 C)
    float m_s = 0.0f, l_s = 0.f;                  // running max (ref 0) / denom

    load_tile(0);
    for (int kt = 0; kt < ntiles; kt++) {
        int kbase = kt * 64;
        __syncthreads();                          // prior iter's LDS reads done
#pragma unroll
        for (int c = 0; c < 6; c++) {
            int idx = t + c * 256;
            int row = idx / 24, col = (idx % 24) * 8;
            *(short8*)(Kl + row * 200 + col) = kreg[c];
        }
#pragma unroll
        for (int c = 0; c < 4; c++) {
            int idx = t + c * 256;
            int row = idx >> 3, col = (idx & 7) * 8;
            *(short8*)(Vl + row * 72 + col) = vreg[c];
        }
        __syncthreads();                          // staging visible to all waves
        if (kt + 1 < ntiles) load_tile(kbase + 64);   // overlaps compute below

        if (kbase > qrow + 31) continue;          // fully-masked for this wave

        // S^T: sacc[kt2][r] = S_log2[key=kbase+kt2*32+(r&3)+8(r>>2)+4hi][q=qrow+ln]
        f32x16 sacc[2] = {};
        __builtin_amdgcn_s_setprio(1);
#pragma unroll
        for (int ks = 0; ks < 12; ks++) {
            short8 ak0 = *(const short8*)(Kl + ln * 200 + ks * 16 + hi * 8);
            short8 ak1 = *(const short8*)(Kl + (32 + ln) * 200 + ks * 16 + hi * 8);
            sacc[0] = __builtin_amdgcn_mfma_f32_32x32x16_bf16(ak0, bq[ks], sacc[0], 0, 0, 0);
            sacc[1] = __builtin_amdgcn_mfma_f32_32x32x16_bf16(ak1, bq[ks], sacc[1], 0, 0, 0);
        }
        __builtin_amdgcn_s_setprio(0);

        if (kbase + 63 > qrow) {                  // diagonal tiles: causal mask (finite)
            int qi = qrow + ln;
#pragma unroll
            for (int kt2 = 0; kt2 < 2; kt2++)
#pragma unroll
                for (int r = 0; r < 16; r++) {
                    int key = kbase + kt2 * 32 + (r & 3) + 8 * (r >> 2) + 4 * hi;
                    if (key > qi) sacc[kt2][r] = NEG;
                }
        }

        // online softmax (log2 domain, ref max 0), lane pair (l, l^32) shares q-row
        float m01 = NEG, m23 = NEG;
#pragma unroll
        for (int r = 0; r < 16; r += 2) {
            m01 = fmaxf(m01, fmaxf(sacc[0][r], sacc[0][r + 1]));
            m23 = fmaxf(m23, fmaxf(sacc[1][r], sacc[1][r + 1]));
        }
        float mx = xhalf_max(fmaxf(m01, m23));
        if (!__all(mx - m_s <= 8.0f)) {           // defer-max (T13): P <= 2^8 otherwise
            float mnew = fmaxf(m_s, mx);
            float alpha = exp2_hw(m_s - mnew);
            m_s = mnew;
            l_s *= alpha;
#pragma unroll
            for (int dt = 0; dt < 4; dt++) o[dt] *= alpha;
        }

        // P = 2^(S-m): exp + cvt_pk + permlane32_swap -> bf16 B-frags fully in-register
        float rs = 0.f;
        short8 bp[2][2];
#pragma unroll
        for (int kt2 = 0; kt2 < 2; kt2++) {
            float p[16];
#pragma unroll
            for (int r = 0; r < 16; r++) p[r] = exp2_hw(sacc[kt2][r] - m_s);
#pragma unroll
            for (int r = 0; r < 16; r += 4)
                rs += (p[r] + p[r + 1]) + (p[r + 2] + p[r + 3]);
            uint32_t c0 = cvtpk(p[0], p[1]),  c1 = cvtpk(p[2], p[3]);
            uint32_t c2 = cvtpk(p[4], p[5]),  c3 = cvtpk(p[6], p[7]);
            permswap(c0, c2); permswap(c1, c3);
            union { uint32_t u[4]; short8 s; } f0 = {{c0, c1, c2, c3}};
            bp[kt2][0] = f0.s;
            uint32_t c4 = cvtpk(p[8], p[9]),   c5 = cvtpk(p[10], p[11]);
            uint32_t c6 = cvtpk(p[12], p[13]), c7 = cvtpk(p[14], p[15]);
            permswap(c4, c6); permswap(c5, c7);
            union { uint32_t u[4]; short8 s; } f1 = {{c4, c5, c6, c7}};
            bp[kt2][1] = f1.s;
        }
        l_s += xhalf_sum(rs);

        // O^T += V^T · P : A=V^T[dim][key] from LDS, B=P[key][q] in regs
        __builtin_amdgcn_s_setprio(1);
#pragma unroll
        for (int kt2 = 0; kt2 < 2; kt2++)
#pragma unroll
            for (int s = 0; s < 2; s++)
#pragma unroll
                for (int dt = 0; dt < 4; dt++) {
                    short8 av = *(const short8*)(Vl + (dt * 32 + ln) * 72 + kt2 * 32 + s * 16 + hi * 8);
                    o[dt] = __builtin_amdgcn_mfma_f32_32x32x16_bf16(av, bp[kt2][s], o[dt], 0, 0, 0);
                }
        __builtin_amdgcn_s_setprio(0);
    }

    // epilogue: C col=q=ln, row=dim=dt*32+(r&3)+8*(r>>2)+4hi -> 4-consecutive-dim packs
    float inv = 1.0f / l_s;
    u16* orow = out + (size_t)(b * S + qrow + ln) * 2048 + h * 128;
#pragma unroll
    for (int dt = 0; dt < 4; dt++)
#pragma unroll
        for (int g = 0; g < 4; g++) {
            ushort4 pk4;
            pk4.x = f2bf(o[dt][g * 4 + 0] * inv);
            pk4.y = f2bf(o[dt][g * 4 + 1] * inv);
            pk4.z = f2bf(o[dt][g * 4 + 2] * inv);
            pk4.w = f2bf(o[dt][g * 4 + 3] * inv);
            *(ushort4*)(orow + dt * 32 + g * 8 + hi * 4) = pk4;
        }
}

extern "C" void kernel_launch(void* const* d_in, const int* in_sizes, int n_in,
                              void* d_out, int out_size, void* d_ws, size_t ws_size,
                              hipStream_t stream) {
    const int B = 2, S = 2048, D = 2048, H = 16;
    const int M = B * S;                       // 4096
    const int NPpad = 3840;                    // 15 tiles of 256 (cols 3648.. are pad)
    // 1/sqrt(192) * log2(e): softmax runs in exp2 domain (folded into Wq/Wq_rope)
    const float scale = 0.07216878364870323f * 1.4426950408889634f;
    const float* x    = (const float*)d_in[0];
    const float* Wq   = (const float*)d_in[1];
    const float* Wqr  = (const float*)d_in[2];
    const float* Wkvd = (const float*)d_in[3];
    const float* Wkvu = (const float*)d_in[4];
    const float* Wkr  = (const float*)d_in[5];
    const float* Wo   = (const float*)d_in[6];

    u16* p = (u16*)d_ws;
    u16* xb     = p; p += (size_t)M * D;             // 16.8 MB
    u16* WprojT = p; p += (size_t)NPpad * 2048;      // rows: [Wq|Wqr|Wkvd|Wkr|pad]
    u16* WkvuT  = p; p += (size_t)4096 * 512;
    u16* WoT    = p; p += (size_t)2048 * 2048;
    u16* proj   = p; p += (size_t)M * NPpad;         // [q_c|q_r|c_kv|k_r|pad] row-major
    u16* kv     = p; p += (size_t)M * 4096;
    u16* v_t    = p; p += (size_t)B * H * 128 * S;
    u16* attn   = p; p += (size_t)M * 2048;

    u16* q_c = proj;                 // cols 0..2047
    u16* q_r = proj + 2048;          // cols 2048..3071
    u16* ckv = proj + 3072;          // cols 3072..3583
    u16* k_r = proj + 3584;          // cols 3584..3647 (3648.. = pad, never read)

    // 1) casts / transposes (Wq, Wq_rope pre-scaled by 1/sqrt(192)*log2e)
    cast_f32_bf16<<<(M * D) / 4 / 256, 256, 0, stream>>>(x, xb, M * D);
    transpose_cast<<<dim3(32, 32), 256, 0, stream>>>(Wq,   WprojT,               2048, 2048, scale);
    transpose_cast<<<dim3(32, 16), 256, 0, stream>>>(Wqr,  WprojT + 2048 * 2048, 2048, 1024, scale);
    transpose_cast<<<dim3(32, 8),  256, 0, stream>>>(Wkvd, WprojT + 3072 * 2048, 2048, 512, 1.0f);
    transpose_cast<<<dim3(32, 1),  256, 0, stream>>>(Wkr,  WprojT + 3584 * 2048, 2048, 64, 1.0f);
    transpose_cast<<<dim3(8, 64),  256, 0, stream>>>(Wkvu, WkvuT, 512, 4096, 1.0f);
    transpose_cast<<<dim3(32, 32), 256, 0, stream>>>(Wo,   WoT,   2048, 2048, 1.0f);

    // 2) merged projection GEMM (256^2 counted-vmcnt): proj = xb @ WprojT^T
    gemm256<2048><<<dim3(16, 15), 512, 0, stream>>>(xb, 2048, WprojT, proj, NPpad);

    // 3) RoPE (in place on proj slices; q_r pre-scaled — rotation linear, scale commutes)
    rope_kernel<<<(M * 16 * 32) / 256, 256, 0, stream>>>(q_r, M, 16, S - 1, NPpad);
    rope_kernel<<<(M * 32) / 256, 256, 0, stream>>>(k_r, M, 1, S - 1, NPpad);

    // 4) kv up-projection (256^2 counted-vmcnt; A = c_kv inside proj), V transpose
    gemm256<512><<<dim3(16, 16), 512, 0, stream>>>(ckv, NPpad, WkvuT, kv, 4096);
    transpose_v<<<dim3(32, 2, 32), 256, 0, stream>>>(kv, v_t, S);

    // 5) attention — grid (bh, 16 q-tiles of 128): pair-balanced, XCD/CU-pinned
    mla_attn<<<dim3(32, 16), 256, 0, stream>>>(q_c, NPpad, q_r, NPpad, kv, k_r, NPpad,
                                               v_t, attn, S);

    // 6) output projection -> fp32 d_out
    gemm_bt<1, 2048, 2048><<<dim3(32, 16), 256, 0, stream>>>(attn, 2048, WoT, d_out, 2048);
}

// Round 8
// 375.134 us; speedup vs baseline: 1.5258x; 1.0246x over previous
//
#include <hip/hip_runtime.h>
#include <hip/hip_bf16.h>
#include <cstdint>
#include <cstddef>

typedef unsigned short u16;
typedef __attribute__((ext_vector_type(8))) short short8;   // 8 bf16 = 4 VGPRs (MFMA A/B frag)
typedef __attribute__((ext_vector_type(4))) float f32x4;    // MFMA C/D frag (16x16)
typedef __attribute__((ext_vector_type(16))) float f32x16;  // MFMA C/D frag (32x32)

__device__ __forceinline__ u16 f2bf(float f) {
    union { float f; uint32_t u; } v; v.f = f;
    uint32_t u = v.u;
    return (u16)((u + 0x7fffu + ((u >> 16) & 1u)) >> 16);   // RNE
}
__device__ __forceinline__ float bf2f(u16 u) {
    union { uint32_t u; float f; } v; v.u = ((uint32_t)u) << 16;
    return v.f;
}
// raw v_exp_f32 (2^x): single HW op (args finite, large-neg -> 0)
__device__ __forceinline__ float exp2_hw(float x) {
    float r;
    asm("v_exp_f32 %0, %1" : "=v"(r) : "v"(x));
    return r;
}
// v_cvt_pk_bf16_f32: dword = {bf16(lo) | bf16(hi)<<16}, RNE
__device__ __forceinline__ uint32_t cvtpk(float lo, float hi) {
    uint32_t r;
    asm("v_cvt_pk_bf16_f32 %0, %1, %2" : "=v"(r) : "v"(lo), "v"(hi));
    return r;
}
// v_permlane32_swap_b32: swaps a's upper-32-lane halves with b's lower-32-lane halves
__device__ __forceinline__ void permswap(uint32_t& a, uint32_t& b) {
    asm("v_permlane32_swap_b32 %0, %1" : "+v"(a), "+v"(b));
}
__device__ __forceinline__ float xhalf_max(float x) {
    union { float f; uint32_t u; } a, b; a.f = x; b.f = x;
    permswap(a.u, b.u);
    return fmaxf(a.f, b.f);
}
__device__ __forceinline__ float xhalf_sum(float x) {
    union { float f; uint32_t u; } a, b; a.f = x; b.f = x;
    permswap(a.u, b.u);
    return a.f + b.f;
}

// async global->LDS 16B copy (global_load_lds_dwordx4). LDS dest = wave-uniform base.
__device__ __forceinline__ void async_cp16(const u16* g, u16* l) {
    __builtin_amdgcn_global_load_lds(
        (const __attribute__((address_space(1))) unsigned int*)g,
        (__attribute__((address_space(3))) unsigned int*)l, 16, 0, 0);
}

// ---------------- cast fp32 -> bf16 (vectorized) ----------------
__global__ __launch_bounds__(256) void cast_f32_bf16(const float* __restrict__ in,
                                                     u16* __restrict__ out, int n) {
    int i = (blockIdx.x * 256 + threadIdx.x) * 4;
    if (i >= n) return;
    float4 v = *(const float4*)(in + i);
    ushort4 r;
    r.x = f2bf(v.x); r.y = f2bf(v.y); r.z = f2bf(v.z); r.w = f2bf(v.w);
    *(ushort4*)(out + i) = r;
}

// ---------------- W (K,N) fp32 -> Wt (N,K) bf16 (optionally pre-scaled) ----------------
__global__ __launch_bounds__(256) void transpose_cast(const float* __restrict__ W,
                                                      u16* __restrict__ Wt, int K, int N,
                                                      float smul) {
    __shared__ u16 tile[64][72];
    int kt = blockIdx.x * 64, nt = blockIdx.y * 64;
    int t = threadIdx.x;
#pragma unroll
    for (int i = 0; i < 16; i++) {
        int idx = t + i * 256; int kl = idx >> 6, nl = idx & 63;
        tile[kl][nl] = f2bf(W[(size_t)(kt + kl) * N + nt + nl] * smul);
    }
    __syncthreads();
#pragma unroll
    for (int i = 0; i < 16; i++) {
        int idx = t + i * 256; int nl = idx >> 6, kl = idx & 63;
        Wt[(size_t)(nt + nl) * K + kt + kl] = tile[kl][nl];
    }
}

// ---------------- bf16 GEMM (m97 structure) — kept for the Wo projection ----------------
template <int OUTF32, int KDIM, int NDIM>
__global__ __launch_bounds__(256) void gemm_bt(const u16* __restrict__ A, int lda,
                                               const u16* __restrict__ Bt,
                                               void* __restrict__ Cout, int ldc) {
    __shared__ __align__(16) u16 Al[128 * 32];
    __shared__ __align__(16) u16 Bl[128 * 32];
    int m0 = blockIdx.x * 128, n0 = blockIdx.y * 128;
    int t = threadIdx.x;
    int w = t >> 6, l = t & 63;
    int lm = l & 15, lq = l >> 4;
    int wm = (w >> 1) * 64, wn = (w & 1) * 64;
    f32x4 acc[4][4] = {};

    for (int k0 = 0; k0 < KDIM; k0 += 32) {
#pragma unroll
        for (int c = 0; c < 2; c++) {
            int chunk = w * 128 + c * 64 + l;
            int row = chunk >> 2, col8 = (chunk & 3) * 8;
            async_cp16(A + (size_t)(m0 + row) * lda + k0 + col8,
                       Al + (w * 128 + c * 64) * 8);
            int brow = n0 + row;
            if (NDIM % 128 != 0) { if (brow >= NDIM) brow = NDIM - 1; }
            async_cp16(Bt + (size_t)brow * KDIM + k0 + col8,
                       Bl + (w * 128 + c * 64) * 8);
        }
        __syncthreads();
        short8 af[4], bfr[4];
#pragma unroll
        for (int mt = 0; mt < 4; mt++)
            af[mt] = *(const short8*)(Al + (wm + mt * 16 + lm) * 32 + lq * 8);
#pragma unroll
        for (int nt = 0; nt < 4; nt++)
            bfr[nt] = *(const short8*)(Bl + (wn + nt * 16 + lm) * 32 + lq * 8);
#pragma unroll
        for (int mt = 0; mt < 4; mt++)
#pragma unroll
            for (int nt = 0; nt < 4; nt++)
                acc[mt][nt] = __builtin_amdgcn_mfma_f32_16x16x32_bf16(af[mt], bfr[nt], acc[mt][nt], 0, 0, 0);
        __syncthreads();
    }
#pragma unroll
    for (int mt = 0; mt < 4; mt++) {
#pragma unroll
        for (int nt = 0; nt < 4; nt++) {
            int col = n0 + wn + nt * 16 + lm;
            if (col < NDIM) {
#pragma unroll
                for (int r = 0; r < 4; r++) {
                    int row = m0 + wm + mt * 16 + lq * 4 + r;
                    if (OUTF32) ((float*)Cout)[(size_t)row * ldc + col] = acc[mt][nt][r];
                    else        ((u16*)Cout)[(size_t)row * ldc + col] = f2bf(acc[mt][nt][r]);
                }
            }
        }
    }
}

// ---------------- 128x256 bf16 GEMM: BK=32, ring-3 LDS, counted vmcnt, 2 blocks/CU ----------------
// Round-7 post-mortem: 256^2/512-thr/128KB ran 1 block/CU in barrier LOCKSTEP — ~2000
// cyc/K-step stalled with both pipes idle (MfmaUtil 29%). Fix: same proven staging/
// swizzle/counted-vmcnt structure, retiled so TWO blocks co-reside per CU — one block's
// vmcnt/barrier stalls are covered by the other's MFMA+DS work (m114 mechanism).
//  * 256 thr = 4 waves (1M x 4N); wave tile 128x64; acc 8x4 f32x4.
//  * ring-3 x BK=32 (72 KB): distance-2 prefetch — write (t+2)%3 while reading t%3,
//    (t+1)%3 idle-ready (no WAR). vmcnt(6) per step (6 loads/thread/step), 0 only at tail.
//  * cross-wave staging safety: each wave waits ITS OWN vmcnt before s_barrier =>
//    after barrier ALL waves' stage(ks+1) loads have retired.
//  * T2 swizzle both-sides (slot ^ (row>>1)&3 on src col and read slot) — conflicts 0.
template <int KDIM>
__global__ __launch_bounds__(256, 2) void gemm_rg(const u16* __restrict__ A, int lda,
                                                  const u16* __restrict__ Bt,
                                                  u16* __restrict__ C, int ldc) {
    __shared__ __align__(16) u16 Ab[3][128 * 32];    // 3 x 8 KB
    __shared__ __align__(16) u16 Bb[3][256 * 32];    // 3 x 16 KB  (72 KB total)
    const int nk = KDIM / 32;
    int m0 = blockIdx.x * 128, n0 = blockIdx.y * 256;
    int t = threadIdx.x, w = t >> 6, l = t & 63;
    int lm = l & 15, lq = l >> 4;
    int wn = w * 64;

    // staging: A = 512 chunks (2 groups), B = 1024 chunks (4 groups); chunk c ->
    // (row=c>>2, slot=c&3) at LDS byte c*16; src col pre-swizzled (slot^((row>>1)&3))*8.
    const u16* Apt[2]; const u16* Bpt[4];
    int ad[2], bd[4];
#pragma unroll
    for (int g = 0; g < 2; g++) {
        int c = t + g * 256, row = c >> 2;
        int col = ((c & 3) ^ ((row >> 1) & 3)) * 8;
        Apt[g] = A + (size_t)(m0 + row) * lda + col;
        ad[g] = (w * 64 + g * 256) * 8;              // wave-uniform LDS base (elems)
    }
#pragma unroll
    for (int g = 0; g < 4; g++) {
        int c = t + g * 256, row = c >> 2;
        int col = ((c & 3) ^ ((row >> 1) & 3)) * 8;
        Bpt[g] = Bt + (size_t)(n0 + row) * KDIM + col;
        bd[g] = (w * 64 + g * 256) * 8;
    }
    auto stage = [&](int ks, int buf) {
        int ko = ks * 32;
#pragma unroll
        for (int g = 0; g < 2; g++) async_cp16(Apt[g] + ko, Ab[buf] + ad[g]);
#pragma unroll
        for (int g = 0; g < 4; g++) async_cp16(Bpt[g] + ko, Bb[buf] + bd[g]);
    };

    // read-side swizzle: row = 16-aligned base + lm -> (row>>1)&3 == (lm>>1)&3
    int slot = (lq ^ ((lm >> 1) & 3)) * 8;

    f32x4 acc[8][4] = {};
    stage(0, 0); stage(1, 1);
    asm volatile("s_waitcnt vmcnt(6)" ::: "memory");  // own stage(0) retired
    __builtin_amdgcn_s_barrier();                     // => everyone's stage(0) retired

    int bc = 0;                                       // ks % 3
    for (int ks = 0; ks < nk; ks++) {
        int bs = (bc + 2 >= 3) ? bc - 1 : bc + 2;     // (ks+2) % 3
        if (ks + 2 < nk) stage(ks + 2, bs);
        const u16* Al = Ab[bc];
        const u16* Bl = Bb[bc];
        short8 bfr[4], af[8];
#pragma unroll
        for (int nt = 0; nt < 4; nt++)
            bfr[nt] = *(const short8*)(Bl + (wn + nt * 16 + lm) * 32 + slot);
#pragma unroll
        for (int mt = 0; mt < 8; mt++)
            af[mt] = *(const short8*)(Al + (mt * 16 + lm) * 32 + slot);
        __builtin_amdgcn_s_setprio(1);
#pragma unroll
        for (int mt = 0; mt < 8; mt++)
#pragma unroll
            for (int nt = 0; nt < 4; nt++)
                acc[mt][nt] = __builtin_amdgcn_mfma_f32_16x16x32_bf16(af[mt], bfr[nt], acc[mt][nt], 0, 0, 0);
        __builtin_amdgcn_s_setprio(0);
        if (ks + 2 < nk)      { asm volatile("s_waitcnt vmcnt(6)" ::: "memory"); }
        else if (ks + 1 < nk) { asm volatile("s_waitcnt vmcnt(0)" ::: "memory"); }
        if (ks + 1 < nk) __builtin_amdgcn_s_barrier();
        bc = (bc + 1 == 3) ? 0 : bc + 1;
    }

#pragma unroll
    for (int mt = 0; mt < 8; mt++)
#pragma unroll
        for (int nt = 0; nt < 4; nt++) {
            int col = n0 + wn + nt * 16 + lm;
            u16* cp = C + (size_t)(m0 + mt * 16 + lq * 4) * ldc + col;
#pragma unroll
            for (int r = 0; r < 4; r++)
                cp[(size_t)r * ldc] = f2bf(acc[mt][nt][r]);
        }
}

// ---------------- RoPE in-place on (rows, nheads*64) bf16, row stride `stride` ----------------
__global__ __launch_bounds__(256) void rope_kernel(u16* __restrict__ x, int rows,
                                                   int nheads, int Smask, int stride) {
    int i = blockIdx.x * 256 + threadIdx.x;
    int total = rows * nheads * 32;
    if (i >= total) return;
    int j = i & 31;
    int h = (i >> 5) % nheads;
    int row = i / (32 * nheads);
    int pos = row & Smask;
    float f = exp2f((float)j * -0.4152410118609828f);
    float ang = (float)pos * f;
    float c = cosf(ang), s = sinf(ang);
    u16* p = x + (size_t)row * stride + h * 64 + j;
    float x1 = bf2f(p[0]), x2 = bf2f(p[32]);
    p[0]  = f2bf(x1 * c - x2 * s);
    p[32] = f2bf(x2 * c + x1 * s);
}

// ---------------- V slice of kv -> v_t (B,H,128,S) bf16 ----------------
__global__ __launch_bounds__(256) void transpose_v(const u16* __restrict__ kv,
                                                   u16* __restrict__ vt, int S) {
    __shared__ u16 tile[64][72];
    int bh = blockIdx.z; int b = bh >> 4, h = bh & 15;
    int s0 = blockIdx.x * 64, d0 = blockIdx.y * 64;
    int t = threadIdx.x;
#pragma unroll
    for (int i = 0; i < 16; i++) {
        int idx = t + i * 256; int sl = idx >> 6, dl = idx & 63;
        tile[sl][dl] = kv[(size_t)(b * S + s0 + sl) * 4096 + 2048 + h * 128 + d0 + dl];
    }
    __syncthreads();
#pragma unroll
    for (int i = 0; i < 16; i++) {
        int idx = t + i * 256; int dl = idx >> 6, sl = idx & 63;
        vt[((size_t)(bh * 128 + d0 + dl)) * S + s0 + sl] = tile[sl][dl];
    }
}

// ---------------- Flash MLA attention v10 (best: ~90us) ----------------
// 32x32 MFMA, 32 q-rows/wave, K/V staged in LDS, P fully in-register via
// cvt_pk + permlane32_swap; defer-max; exp2-domain softmax.
__global__ __launch_bounds__(256, 2) void mla_attn(const u16* __restrict__ qc, int qcs,
                                                   const u16* __restrict__ qr, int qrs,
                                                   const u16* __restrict__ kvbuf,
                                                   const u16* __restrict__ kr, int krs,
                                                   const u16* __restrict__ vt,
                                                   u16* __restrict__ out, int S) {
    __shared__ __align__(16) u16 Kl[64 * 200];       // 64 keys x 192 dims, stride 200
    __shared__ __align__(16) u16 Vl[128 * 72];       // 128 dims x 64 keys, stride 72
    const float NEG = -1e30f;
    int bh = blockIdx.x; int b = bh >> 4, h = bh & 15;   // XCD-pinning: XCD = bh%8
    int y = blockIdx.y;
    int qt = (y < 8) ? (15 - y) : (y - 8);
    int t = threadIdx.x, w = t >> 6, l = t & 63;
    int ln = l & 31, hi = l >> 5;

    short8 kreg[6], vreg[4];
    auto load_tile = [&](int kbase) {
#pragma unroll
        for (int c = 0; c < 6; c++) {                 // K: 64 rows x 24 chunks(16B)
            int idx = t + c * 256;
            int row = idx / 24, col = (idx % 24) * 8;
            const u16* src = (col < 128)
                ? kvbuf + (size_t)(b * S + kbase + row) * 4096 + h * 128 + col
                : kr + (size_t)(b * S + kbase + row) * krs + (col - 128);
            kreg[c] = *(const short8*)src;
        }
#pragma unroll
        for (int c = 0; c < 4; c++) {                 // V^T: 128 rows x 8 chunks(16B)
            int idx = t + c * 256;
            int row = idx >> 3, col = (idx & 7) * 8;
            vreg[c] = *(const short8*)(vt + ((size_t)bh * 128 + row) * S + kbase + col);
        }
    };

    int qrow = qt * 128 + w * 32;                     // this wave's 32 q-rows
    int ntiles = 2 * qt + 2;

    // Q B-frags for 32x32x16: lane holds col q=ln, k = ks*16 + hi*8 + j (pre-scaled)
    short8 bq[12];
    {
        const u16* qc_row = qc + (size_t)(b * S + qrow + ln) * qcs + h * 128;
#pragma unroll
        for (int ks = 0; ks < 8; ks++) bq[ks] = *(const short8*)(qc_row + ks * 16 + hi * 8);
        const u16* qr_row = qr + (size_t)(b * S + qrow + ln) * qrs + h * 64;
#pragma unroll
        for (int ks = 0; ks < 4; ks++) bq[8 + ks] = *(const short8*)(qr_row + ks * 16 + hi * 8);
    }

    f32x16 o[4] = {};                             // O^T: 4 dim-tiles x (32x32 C)
    float m_s = 0.0f, l_s = 0.f;                  // running max (ref 0) / denom

    load_tile(0);
    for (int kt = 0; kt < ntiles; kt++) {
        int kbase = kt * 64;
        __syncthreads();                          // prior iter's LDS reads done
#pragma unroll
        for (int c = 0; c < 6; c++) {
            int idx = t + c * 256;
            int row = idx / 24, col = (idx % 24) * 8;
            *(short8*)(Kl + row * 200 + col) = kreg[c];
        }
#pragma unroll
        for (int c = 0; c < 4; c++) {
            int idx = t + c * 256;
            int row = idx >> 3, col = (idx & 7) * 8;
            *(short8*)(Vl + row * 72 + col) = vreg[c];
        }
        __syncthreads();                          // staging visible to all waves
        if (kt + 1 < ntiles) load_tile(kbase + 64);   // overlaps compute below

        if (kbase > qrow + 31) continue;          // fully-masked for this wave

        // S^T: sacc[kt2][r] = S_log2[key=kbase+kt2*32+(r&3)+8(r>>2)+4hi][q=qrow+ln]
        f32x16 sacc[2] = {};
        __builtin_amdgcn_s_setprio(1);
#pragma unroll
        for (int ks = 0; ks < 12; ks++) {
            short8 ak0 = *(const short8*)(Kl + ln * 200 + ks * 16 + hi * 8);
            short8 ak1 = *(const short8*)(Kl + (32 + ln) * 200 + ks * 16 + hi * 8);
            sacc[0] = __builtin_amdgcn_mfma_f32_32x32x16_bf16(ak0, bq[ks], sacc[0], 0, 0, 0);
            sacc[1] = __builtin_amdgcn_mfma_f32_32x32x16_bf16(ak1, bq[ks], sacc[1], 0, 0, 0);
        }
        __builtin_amdgcn_s_setprio(0);

        if (kbase + 63 > qrow) {                  // diagonal tiles: causal mask (finite)
            int qi = qrow + ln;
#pragma unroll
            for (int kt2 = 0; kt2 < 2; kt2++)
#pragma unroll
                for (int r = 0; r < 16; r++) {
                    int key = kbase + kt2 * 32 + (r & 3) + 8 * (r >> 2) + 4 * hi;
                    if (key > qi) sacc[kt2][r] = NEG;
                }
        }

        // online softmax (log2 domain, ref max 0), lane pair (l, l^32) shares q-row
        float m01 = NEG, m23 = NEG;
#pragma unroll
        for (int r = 0; r < 16; r += 2) {
            m01 = fmaxf(m01, fmaxf(sacc[0][r], sacc[0][r + 1]));
            m23 = fmaxf(m23, fmaxf(sacc[1][r], sacc[1][r + 1]));
        }
        float mx = xhalf_max(fmaxf(m01, m23));
        if (!__all(mx - m_s <= 8.0f)) {           // defer-max (T13): P <= 2^8 otherwise
            float mnew = fmaxf(m_s, mx);
            float alpha = exp2_hw(m_s - mnew);
            m_s = mnew;
            l_s *= alpha;
#pragma unroll
            for (int dt = 0; dt < 4; dt++) o[dt] *= alpha;
        }

        // P = 2^(S-m): exp + cvt_pk + permlane32_swap -> bf16 B-frags fully in-register
        float rs = 0.f;
        short8 bp[2][2];
#pragma unroll
        for (int kt2 = 0; kt2 < 2; kt2++) {
            float p[16];
#pragma unroll
            for (int r = 0; r < 16; r++) p[r] = exp2_hw(sacc[kt2][r] - m_s);
#pragma unroll
            for (int r = 0; r < 16; r += 4)
                rs += (p[r] + p[r + 1]) + (p[r + 2] + p[r + 3]);
            uint32_t c0 = cvtpk(p[0], p[1]),  c1 = cvtpk(p[2], p[3]);
            uint32_t c2 = cvtpk(p[4], p[5]),  c3 = cvtpk(p[6], p[7]);
            permswap(c0, c2); permswap(c1, c3);
            union { uint32_t u[4]; short8 s; } f0 = {{c0, c1, c2, c3}};
            bp[kt2][0] = f0.s;
            uint32_t c4 = cvtpk(p[8], p[9]),   c5 = cvtpk(p[10], p[11]);
            uint32_t c6 = cvtpk(p[12], p[13]), c7 = cvtpk(p[14], p[15]);
            permswap(c4, c6); permswap(c5, c7);
            union { uint32_t u[4]; short8 s; } f1 = {{c4, c5, c6, c7}};
            bp[kt2][1] = f1.s;
        }
        l_s += xhalf_sum(rs);

        // O^T += V^T · P : A=V^T[dim][key] from LDS, B=P[key][q] in regs
        __builtin_amdgcn_s_setprio(1);
#pragma unroll
        for (int kt2 = 0; kt2 < 2; kt2++)
#pragma unroll
            for (int s = 0; s < 2; s++)
#pragma unroll
                for (int dt = 0; dt < 4; dt++) {
                    short8 av = *(const short8*)(Vl + (dt * 32 + ln) * 72 + kt2 * 32 + s * 16 + hi * 8);
                    o[dt] = __builtin_amdgcn_mfma_f32_32x32x16_bf16(av, bp[kt2][s], o[dt], 0, 0, 0);
                }
        __builtin_amdgcn_s_setprio(0);
    }

    // epilogue: C col=q=ln, row=dim=dt*32+(r&3)+8*(r>>2)+4hi -> 4-consecutive-dim packs
    float inv = 1.0f / l_s;
    u16* orow = out + (size_t)(b * S + qrow + ln) * 2048 + h * 128;
#pragma unroll
    for (int dt = 0; dt < 4; dt++)
#pragma unroll
        for (int g = 0; g < 4; g++) {
            ushort4 pk4;
            pk4.x = f2bf(o[dt][g * 4 + 0] * inv);
            pk4.y = f2bf(o[dt][g * 4 + 1] * inv);
            pk4.z = f2bf(o[dt][g * 4 + 2] * inv);
            pk4.w = f2bf(o[dt][g * 4 + 3] * inv);
            *(ushort4*)(orow + dt * 32 + g * 8 + hi * 4) = pk4;
        }
}

extern "C" void kernel_launch(void* const* d_in, const int* in_sizes, int n_in,
                              void* d_out, int out_size, void* d_ws, size_t ws_size,
                              hipStream_t stream) {
    const int B = 2, S = 2048, D = 2048, H = 16;
    const int M = B * S;                       // 4096
    const int NPpad = 3840;                    // 15 tiles of 256 (cols 3648.. are pad)
    // 1/sqrt(192) * log2(e): softmax runs in exp2 domain (folded into Wq/Wq_rope)
    const float scale = 0.07216878364870323f * 1.4426950408889634f;
    const float* x    = (const float*)d_in[0];
    const float* Wq   = (const float*)d_in[1];
    const float* Wqr  = (const float*)d_in[2];
    const float* Wkvd = (const float*)d_in[3];
    const float* Wkvu = (const float*)d_in[4];
    const float* Wkr  = (const float*)d_in[5];
    const float* Wo   = (const float*)d_in[6];

    u16* p = (u16*)d_ws;
    u16* xb     = p; p += (size_t)M * D;             // 16.8 MB
    u16* WprojT = p; p += (size_t)NPpad * 2048;      // rows: [Wq|Wqr|Wkvd|Wkr|pad]
    u16* WkvuT  = p; p += (size_t)4096 * 512;
    u16* WoT    = p; p += (size_t)2048 * 2048;
    u16* proj   = p; p += (size_t)M * NPpad;         // [q_c|q_r|c_kv|k_r|pad] row-major
    u16* kv     = p; p += (size_t)M * 4096;
    u16* v_t    = p; p += (size_t)B * H * 128 * S;
    u16* attn   = p; p += (size_t)M * 2048;

    u16* q_c = proj;                 // cols 0..2047
    u16* q_r = proj + 2048;          // cols 2048..3071
    u16* ckv = proj + 3072;          // cols 3072..3583
    u16* k_r = proj + 3584;          // cols 3584..3647 (3648.. = pad, never read)

    // 1) casts / transposes (Wq, Wq_rope pre-scaled by 1/sqrt(192)*log2e)
    cast_f32_bf16<<<(M * D) / 4 / 256, 256, 0, stream>>>(x, xb, M * D);
    transpose_cast<<<dim3(32, 32), 256, 0, stream>>>(Wq,   WprojT,               2048, 2048, scale);
    transpose_cast<<<dim3(32, 16), 256, 0, stream>>>(Wqr,  WprojT + 2048 * 2048, 2048, 1024, scale);
    transpose_cast<<<dim3(32, 8),  256, 0, stream>>>(Wkvd, WprojT + 3072 * 2048, 2048, 512, 1.0f);
    transpose_cast<<<dim3(32, 1),  256, 0, stream>>>(Wkr,  WprojT + 3584 * 2048, 2048, 64, 1.0f);
    transpose_cast<<<dim3(8, 64),  256, 0, stream>>>(Wkvu, WkvuT, 512, 4096, 1.0f);
    transpose_cast<<<dim3(32, 32), 256, 0, stream>>>(Wo,   WoT,   2048, 2048, 1.0f);

    // 2) merged projection GEMM (128x256 ring-3, 2 blocks/CU): proj = xb @ WprojT^T
    gemm_rg<2048><<<dim3(32, 15), 256, 0, stream>>>(xb, 2048, WprojT, proj, NPpad);

    // 3) RoPE (in place on proj slices; q_r pre-scaled — rotation linear, scale commutes)
    rope_kernel<<<(M * 16 * 32) / 256, 256, 0, stream>>>(q_r, M, 16, S - 1, NPpad);
    rope_kernel<<<(M * 32) / 256, 256, 0, stream>>>(k_r, M, 1, S - 1, NPpad);

    // 4) kv up-projection (128x256 ring-3; A = c_kv inside proj), V transpose
    gemm_rg<512><<<dim3(32, 16), 256, 0, stream>>>(ckv, NPpad, WkvuT, kv, 4096);
    transpose_v<<<dim3(32, 2, 32), 256, 0, stream>>>(kv, v_t, S);

    // 5) attention — grid (bh, 16 q-tiles of 128): pair-balanced, XCD/CU-pinned
    mla_attn<<<dim3(32, 16), 256, 0, stream>>>(q_c, NPpad, q_r, NPpad, kv, k_r, NPpad,
                                               v_t, attn, S);

    // 6) output projection -> fp32 d_out
    gemm_bt<1, 2048, 2048><<<dim3(32, 16), 256, 0, stream>>>(attn, 2048, WoT, d_out, 2048);
}

// Round 9
// 373.631 us; speedup vs baseline: 1.5319x; 1.0040x over previous
//
#include <hip/hip_runtime.h>
#include <hip/hip_bf16.h>
#include <cstdint>
#include <cstddef>

typedef unsigned short u16;
typedef __attribute__((ext_vector_type(8))) short short8;   // 8 bf16 = 4 VGPRs (MFMA A/B frag)
typedef __attribute__((ext_vector_type(4))) float f32x4;    // MFMA C/D frag (16x16)
typedef __attribute__((ext_vector_type(16))) float f32x16;  // MFMA C/D frag (32x32)

__device__ __forceinline__ u16 f2bf(float f) {
    union { float f; uint32_t u; } v; v.f = f;
    uint32_t u = v.u;
    return (u16)((u + 0x7fffu + ((u >> 16) & 1u)) >> 16);   // RNE
}
__device__ __forceinline__ float bf2f(u16 u) {
    union { uint32_t u; float f; } v; v.u = ((uint32_t)u) << 16;
    return v.f;
}
// raw v_exp_f32 (2^x): single HW op (args finite, large-neg -> 0)
__device__ __forceinline__ float exp2_hw(float x) {
    float r;
    asm("v_exp_f32 %0, %1" : "=v"(r) : "v"(x));
    return r;
}
// v_cvt_pk_bf16_f32: dword = {bf16(lo) | bf16(hi)<<16}, RNE
__device__ __forceinline__ uint32_t cvtpk(float lo, float hi) {
    uint32_t r;
    asm("v_cvt_pk_bf16_f32 %0, %1, %2" : "=v"(r) : "v"(lo), "v"(hi));
    return r;
}
// v_permlane32_swap_b32: swaps a's upper-32-lane halves with b's lower-32-lane halves
__device__ __forceinline__ void permswap(uint32_t& a, uint32_t& b) {
    asm("v_permlane32_swap_b32 %0, %1" : "+v"(a), "+v"(b));
}
__device__ __forceinline__ float xhalf_max(float x) {
    union { float f; uint32_t u; } a, b; a.f = x; b.f = x;
    permswap(a.u, b.u);
    return fmaxf(a.f, b.f);
}
__device__ __forceinline__ float xhalf_sum(float x) {
    union { float f; uint32_t u; } a, b; a.f = x; b.f = x;
    permswap(a.u, b.u);
    return a.f + b.f;
}

// async global->LDS 16B copy (global_load_lds_dwordx4). LDS dest = wave-uniform base.
__device__ __forceinline__ void async_cp16(const u16* g, u16* l) {
    __builtin_amdgcn_global_load_lds(
        (const __attribute__((address_space(1))) unsigned int*)g,
        (__attribute__((address_space(3))) unsigned int*)l, 16, 0, 0);
}

// ---------------- cast fp32 -> bf16 (vectorized) ----------------
__global__ __launch_bounds__(256) void cast_f32_bf16(const float* __restrict__ in,
                                                     u16* __restrict__ out, int n) {
    int i = (blockIdx.x * 256 + threadIdx.x) * 4;
    if (i >= n) return;
    float4 v = *(const float4*)(in + i);
    ushort4 r;
    r.x = f2bf(v.x); r.y = f2bf(v.y); r.z = f2bf(v.z); r.w = f2bf(v.w);
    *(ushort4*)(out + i) = r;
}

// ---------------- ALL weight transposes fused in one launch ----------------
// Round-8: ~110us of the 375 is unaccounted -> inter-dispatch gaps across 14 launches.
// Fuse the 6 transpose_cast launches into 1 (compile-time range table, body identical).
__global__ __launch_bounds__(256) void transpose_cast_all(
    const float* __restrict__ Wq, const float* __restrict__ Wqr,
    const float* __restrict__ Wkvd, const float* __restrict__ Wkr,
    const float* __restrict__ Wkvu, const float* __restrict__ Wo,
    u16* __restrict__ WprojT, u16* __restrict__ WkvuT, u16* __restrict__ WoT,
    float scale) {
    int id = blockIdx.x;
    const float* W; u16* Wt; int K, N, ktiles, tid; float smul;
    if (id < 1024)      { W = Wq;   Wt = WprojT;              K = 2048; N = 2048; ktiles = 32; tid = id;        smul = scale; }
    else if (id < 1536) { W = Wqr;  Wt = WprojT + 2048*2048;  K = 2048; N = 1024; ktiles = 32; tid = id - 1024; smul = scale; }
    else if (id < 1792) { W = Wkvd; Wt = WprojT + 3072*2048;  K = 2048; N = 512;  ktiles = 32; tid = id - 1536; smul = 1.0f; }
    else if (id < 1824) { W = Wkr;  Wt = WprojT + 3584*2048;  K = 2048; N = 64;   ktiles = 32; tid = id - 1792; smul = 1.0f; }
    else if (id < 2336) { W = Wkvu; Wt = WkvuT;               K = 512;  N = 4096; ktiles = 8;  tid = id - 1824; smul = 1.0f; }
    else                { W = Wo;   Wt = WoT;                 K = 2048; N = 2048; ktiles = 32; tid = id - 2336; smul = 1.0f; }
    int kt = (tid % ktiles) * 64, nt = (tid / ktiles) * 64;
    __shared__ u16 tile[64][72];
    int t = threadIdx.x;
#pragma unroll
    for (int i = 0; i < 16; i++) {
        int idx = t + i * 256; int kl = idx >> 6, nl = idx & 63;
        tile[kl][nl] = f2bf(W[(size_t)(kt + kl) * N + nt + nl] * smul);
    }
    __syncthreads();
#pragma unroll
    for (int i = 0; i < 16; i++) {
        int idx = t + i * 256; int nl = idx >> 6, kl = idx & 63;
        Wt[(size_t)(nt + nl) * K + kt + kl] = tile[kl][nl];
    }
}

// ---------------- bf16 GEMM (m97 structure) — kept for the Wo projection ----------------
template <int OUTF32, int KDIM, int NDIM>
__global__ __launch_bounds__(256) void gemm_bt(const u16* __restrict__ A, int lda,
                                               const u16* __restrict__ Bt,
                                               void* __restrict__ Cout, int ldc) {
    __shared__ __align__(16) u16 Al[128 * 32];
    __shared__ __align__(16) u16 Bl[128 * 32];
    int m0 = blockIdx.x * 128, n0 = blockIdx.y * 128;
    int t = threadIdx.x;
    int w = t >> 6, l = t & 63;
    int lm = l & 15, lq = l >> 4;
    int wm = (w >> 1) * 64, wn = (w & 1) * 64;
    f32x4 acc[4][4] = {};

    for (int k0 = 0; k0 < KDIM; k0 += 32) {
#pragma unroll
        for (int c = 0; c < 2; c++) {
            int chunk = w * 128 + c * 64 + l;
            int row = chunk >> 2, col8 = (chunk & 3) * 8;
            async_cp16(A + (size_t)(m0 + row) * lda + k0 + col8,
                       Al + (w * 128 + c * 64) * 8);
            int brow = n0 + row;
            if (NDIM % 128 != 0) { if (brow >= NDIM) brow = NDIM - 1; }
            async_cp16(Bt + (size_t)brow * KDIM + k0 + col8,
                       Bl + (w * 128 + c * 64) * 8);
        }
        __syncthreads();
        short8 af[4], bfr[4];
#pragma unroll
        for (int mt = 0; mt < 4; mt++)
            af[mt] = *(const short8*)(Al + (wm + mt * 16 + lm) * 32 + lq * 8);
#pragma unroll
        for (int nt = 0; nt < 4; nt++)
            bfr[nt] = *(const short8*)(Bl + (wn + nt * 16 + lm) * 32 + lq * 8);
#pragma unroll
        for (int mt = 0; mt < 4; mt++)
#pragma unroll
            for (int nt = 0; nt < 4; nt++)
                acc[mt][nt] = __builtin_amdgcn_mfma_f32_16x16x32_bf16(af[mt], bfr[nt], acc[mt][nt], 0, 0, 0);
        __syncthreads();
    }
#pragma unroll
    for (int mt = 0; mt < 4; mt++) {
#pragma unroll
        for (int nt = 0; nt < 4; nt++) {
            int col = n0 + wn + nt * 16 + lm;
            if (col < NDIM) {
#pragma unroll
                for (int r = 0; r < 4; r++) {
                    int row = m0 + wm + mt * 16 + lq * 4 + r;
                    if (OUTF32) ((float*)Cout)[(size_t)row * ldc + col] = acc[mt][nt][r];
                    else        ((u16*)Cout)[(size_t)row * ldc + col] = f2bf(acc[mt][nt][r]);
                }
            }
        }
    }
}

// ---------------- 128x256 bf16 GEMM: 32x32x16 MFMA, ring-3 LDS, counted vmcnt ----------------
// Round-8 (16x16 version) = 82us proj, MfmaUtil 33%, conflicts 0. MFMA pipe vs DS pipe
// ~balanced (1240 vs 1150 cyc/CU/K-step). Upgrade to mfma_32x32x16 (m119: 8.07cyc vs
// 2x4.85 = ~17% less MFMA-pipe time; half the instruction issue). DS reads unchanged
// (8 A + 4 B b128/wave-step); ring/staging/swizzle/vmcnt byte-identical to round 8.
// A/B/C 32x32 layouts = the conventions verified in attn v7 (A: m=ln,k=hi*8+j;
// C: col=ln, row=(r&3)+8(r>>2)+4hi). Swizzle bank check (per quarter-wave = 16 lanes):
// 2 lanes per 4-bank window -> 2-way = free (m136).
template <int KDIM>
__global__ __launch_bounds__(256, 2) void gemm_rg(const u16* __restrict__ A, int lda,
                                                  const u16* __restrict__ Bt,
                                                  u16* __restrict__ C, int ldc) {
    __shared__ __align__(16) u16 Ab[3][128 * 32];    // 3 x 8 KB
    __shared__ __align__(16) u16 Bb[3][256 * 32];    // 3 x 16 KB  (72 KB total)
    const int nk = KDIM / 32;
    int m0 = blockIdx.x * 128, n0 = blockIdx.y * 256;
    int t = threadIdx.x, w = t >> 6, l = t & 63;
    int ln = l & 31, hi = l >> 5;
    int wn = w * 64;

    // staging: A = 512 chunks (2 groups), B = 1024 chunks (4 groups); chunk c ->
    // (row=c>>2, slot=c&3) at LDS byte c*16; src col pre-swizzled (slot^((row>>1)&3))*8.
    const u16* Apt[2]; const u16* Bpt[4];
    int ad[2], bd[4];
#pragma unroll
    for (int g = 0; g < 2; g++) {
        int c = t + g * 256, row = c >> 2;
        int col = ((c & 3) ^ ((row >> 1) & 3)) * 8;
        Apt[g] = A + (size_t)(m0 + row) * lda + col;
        ad[g] = (w * 64 + g * 256) * 8;              // wave-uniform LDS base (elems)
    }
#pragma unroll
    for (int g = 0; g < 4; g++) {
        int c = t + g * 256, row = c >> 2;
        int col = ((c & 3) ^ ((row >> 1) & 3)) * 8;
        Bpt[g] = Bt + (size_t)(n0 + row) * KDIM + col;
        bd[g] = (w * 64 + g * 256) * 8;
    }
    auto stage = [&](int ks, int buf) {
        int ko = ks * 32;
#pragma unroll
        for (int g = 0; g < 2; g++) async_cp16(Apt[g] + ko, Ab[buf] + ad[g]);
#pragma unroll
        for (int g = 0; g < 4; g++) async_cp16(Bpt[g] + ko, Bb[buf] + bd[g]);
    };

    // read-side swizzle nibble: sw = (ln>>1)&3 (row = 32-aligned base + ln)
    int sw = (ln >> 1) & 3;

    f32x16 acc[4][2] = {};
    stage(0, 0); stage(1, 1);
    asm volatile("s_waitcnt vmcnt(6)" ::: "memory");  // own stage(0) retired
    __builtin_amdgcn_s_barrier();                     // => everyone's stage(0) retired

    int bc = 0;                                       // ks % 3
    for (int ks = 0; ks < nk; ks++) {
        int bs = (bc + 2 >= 3) ? bc - 1 : bc + 2;     // (ks+2) % 3
        if (ks + 2 < nk) stage(ks + 2, bs);
        const u16* Al = Ab[bc];
        const u16* Bl = Bb[bc];
        short8 af[4][2], bfr[2][2];
#pragma unroll
        for (int nt = 0; nt < 2; nt++)
#pragma unroll
            for (int kk = 0; kk < 2; kk++)
                bfr[nt][kk] = *(const short8*)(Bl + (wn + nt * 32 + ln) * 32 + ((2 * kk + hi) ^ sw) * 8);
#pragma unroll
        for (int mt = 0; mt < 4; mt++)
#pragma unroll
            for (int kk = 0; kk < 2; kk++)
                af[mt][kk] = *(const short8*)(Al + (mt * 32 + ln) * 32 + ((2 * kk + hi) ^ sw) * 8);
        __builtin_amdgcn_s_setprio(1);
#pragma unroll
        for (int kk = 0; kk < 2; kk++)
#pragma unroll
            for (int mt = 0; mt < 4; mt++)
#pragma unroll
                for (int nt = 0; nt < 2; nt++)
                    acc[mt][nt] = __builtin_amdgcn_mfma_f32_32x32x16_bf16(af[mt][kk], bfr[nt][kk], acc[mt][nt], 0, 0, 0);
        __builtin_amdgcn_s_setprio(0);
        if (ks + 2 < nk)      { asm volatile("s_waitcnt vmcnt(6)" ::: "memory"); }
        else if (ks + 1 < nk) { asm volatile("s_waitcnt vmcnt(0)" ::: "memory"); }
        if (ks + 1 < nk) __builtin_amdgcn_s_barrier();
        bc = (bc + 1 == 3) ? 0 : bc + 1;
    }

    // C: col = n0+wn+nt*32+ln, row = m0+mt*32+(r&3)+8*(r>>2)+4*hi
#pragma unroll
    for (int mt = 0; mt < 4; mt++)
#pragma unroll
        for (int nt = 0; nt < 2; nt++) {
            int col = n0 + wn + nt * 32 + ln;
            u16* cp = C + (size_t)(m0 + mt * 32 + 4 * hi) * ldc + col;
#pragma unroll
            for (int g = 0; g < 4; g++)
#pragma unroll
                for (int r = 0; r < 4; r++)
                    cp[(size_t)(g * 8 + r) * ldc] = f2bf(acc[mt][nt][g * 4 + r]);
        }
}

// ---------------- RoPE fused: q_r (16 heads) + k_r (1 head at col offset 1536) ----------------
// rows x 17 "heads" x 32 pairs; head 16 = k_r. Both slices share proj's row stride.
__global__ __launch_bounds__(256) void rope_all(u16* __restrict__ xq, int rows,
                                                int Smask, int stride) {
    int i = blockIdx.x * 256 + threadIdx.x;
    if (i >= rows * 17 * 32) return;
    int j = i & 31;
    int h = (i >> 5) % 17;
    int row = i / (32 * 17);
    int pos = row & Smask;
    float f = exp2f((float)j * -0.4152410118609828f);
    float ang = (float)pos * f;
    float c = cosf(ang), s = sinf(ang);
    int coff = (h < 16) ? h * 64 : 1536;         // k_r: proj col 3584 = q_r base + 1536
    u16* p = xq + (size_t)row * stride + coff + j;
    float x1 = bf2f(p[0]), x2 = bf2f(p[32]);
    p[0]  = f2bf(x1 * c - x2 * s);
    p[32] = f2bf(x2 * c + x1 * s);
}

// ---------------- V slice of kv -> v_t (B,H,128,S) bf16 ----------------
__global__ __launch_bounds__(256) void transpose_v(const u16* __restrict__ kv,
                                                   u16* __restrict__ vt, int S) {
    __shared__ u16 tile[64][72];
    int bh = blockIdx.z; int b = bh >> 4, h = bh & 15;
    int s0 = blockIdx.x * 64, d0 = blockIdx.y * 64;
    int t = threadIdx.x;
#pragma unroll
    for (int i = 0; i < 16; i++) {
        int idx = t + i * 256; int sl = idx >> 6, dl = idx & 63;
        tile[sl][dl] = kv[(size_t)(b * S + s0 + sl) * 4096 + 2048 + h * 128 + d0 + dl];
    }
    __syncthreads();
#pragma unroll
    for (int i = 0; i < 16; i++) {
        int idx = t + i * 256; int dl = idx >> 6, sl = idx & 63;
        vt[((size_t)(bh * 128 + d0 + dl)) * S + s0 + sl] = tile[sl][dl];
    }
}

// ---------------- Flash MLA attention v10 (best: <82us) ----------------
// 32x32 MFMA, 32 q-rows/wave, K/V staged in LDS, P fully in-register via
// cvt_pk + permlane32_swap; defer-max; exp2-domain softmax.
__global__ __launch_bounds__(256, 2) void mla_attn(const u16* __restrict__ qc, int qcs,
                                                   const u16* __restrict__ qr, int qrs,
                                                   const u16* __restrict__ kvbuf,
                                                   const u16* __restrict__ kr, int krs,
                                                   const u16* __restrict__ vt,
                                                   u16* __restrict__ out, int S) {
    __shared__ __align__(16) u16 Kl[64 * 200];       // 64 keys x 192 dims, stride 200
    __shared__ __align__(16) u16 Vl[128 * 72];       // 128 dims x 64 keys, stride 72
    const float NEG = -1e30f;
    int bh = blockIdx.x; int b = bh >> 4, h = bh & 15;   // XCD-pinning: XCD = bh%8
    int y = blockIdx.y;
    int qt = (y < 8) ? (15 - y) : (y - 8);
    int t = threadIdx.x, w = t >> 6, l = t & 63;
    int ln = l & 31, hi = l >> 5;

    short8 kreg[6], vreg[4];
    auto load_tile = [&](int kbase) {
#pragma unroll
        for (int c = 0; c < 6; c++) {                 // K: 64 rows x 24 chunks(16B)
            int idx = t + c * 256;
            int row = idx / 24, col = (idx % 24) * 8;
            const u16* src = (col < 128)
                ? kvbuf + (size_t)(b * S + kbase + row) * 4096 + h * 128 + col
                : kr + (size_t)(b * S + kbase + row) * krs + (col - 128);
            kreg[c] = *(const short8*)src;
        }
#pragma unroll
        for (int c = 0; c < 4; c++) {                 // V^T: 128 rows x 8 chunks(16B)
            int idx = t + c * 256;
            int row = idx >> 3, col = (idx & 7) * 8;
            vreg[c] = *(const short8*)(vt + ((size_t)bh * 128 + row) * S + kbase + col);
        }
    };

    int qrow = qt * 128 + w * 32;                     // this wave's 32 q-rows
    int ntiles = 2 * qt + 2;

    // Q B-frags for 32x32x16: lane holds col q=ln, k = ks*16 + hi*8 + j (pre-scaled)
    short8 bq[12];
    {
        const u16* qc_row = qc + (size_t)(b * S + qrow + ln) * qcs + h * 128;
#pragma unroll
        for (int ks = 0; ks < 8; ks++) bq[ks] = *(const short8*)(qc_row + ks * 16 + hi * 8);
        const u16* qr_row = qr + (size_t)(b * S + qrow + ln) * qrs + h * 64;
#pragma unroll
        for (int ks = 0; ks < 4; ks++) bq[8 + ks] = *(const short8*)(qr_row + ks * 16 + hi * 8);
    }

    f32x16 o[4] = {};                             // O^T: 4 dim-tiles x (32x32 C)
    float m_s = 0.0f, l_s = 0.f;                  // running max (ref 0) / denom

    load_tile(0);
    for (int kt = 0; kt < ntiles; kt++) {
        int kbase = kt * 64;
        __syncthreads();                          // prior iter's LDS reads done
#pragma unroll
        for (int c = 0; c < 6; c++) {
            int idx = t + c * 256;
            int row = idx / 24, col = (idx % 24) * 8;
            *(short8*)(Kl + row * 200 + col) = kreg[c];
        }
#pragma unroll
        for (int c = 0; c < 4; c++) {
            int idx = t + c * 256;
            int row = idx >> 3, col = (idx & 7) * 8;
            *(short8*)(Vl + row * 72 + col) = vreg[c];
        }
        __syncthreads();                          // staging visible to all waves
        if (kt + 1 < ntiles) load_tile(kbase + 64);   // overlaps compute below

        if (kbase > qrow + 31) continue;          // fully-masked for this wave

        // S^T: sacc[kt2][r] = S_log2[key=kbase+kt2*32+(r&3)+8(r>>2)+4hi][q=qrow+ln]
        f32x16 sacc[2] = {};
        __builtin_amdgcn_s_setprio(1);
#pragma unroll
        for (int ks = 0; ks < 12; ks++) {
            short8 ak0 = *(const short8*)(Kl + ln * 200 + ks * 16 + hi * 8);
            short8 ak1 = *(const short8*)(Kl + (32 + ln) * 200 + ks * 16 + hi * 8);
            sacc[0] = __builtin_amdgcn_mfma_f32_32x32x16_bf16(ak0, bq[ks], sacc[0], 0, 0, 0);
            sacc[1] = __builtin_amdgcn_mfma_f32_32x32x16_bf16(ak1, bq[ks], sacc[1], 0, 0, 0);
        }
        __builtin_amdgcn_s_setprio(0);

        if (kbase + 63 > qrow) {                  // diagonal tiles: causal mask (finite)
            int qi = qrow + ln;
#pragma unroll
            for (int kt2 = 0; kt2 < 2; kt2++)
#pragma unroll
                for (int r = 0; r < 16; r++) {
                    int key = kbase + kt2 * 32 + (r & 3) + 8 * (r >> 2) + 4 * hi;
                    if (key > qi) sacc[kt2][r] = NEG;
                }
        }

        // online softmax (log2 domain, ref max 0), lane pair (l, l^32) shares q-row
        float m01 = NEG, m23 = NEG;
#pragma unroll
        for (int r = 0; r < 16; r += 2) {
            m01 = fmaxf(m01, fmaxf(sacc[0][r], sacc[0][r + 1]));
            m23 = fmaxf(m23, fmaxf(sacc[1][r], sacc[1][r + 1]));
        }
        float mx = xhalf_max(fmaxf(m01, m23));
        if (!__all(mx - m_s <= 8.0f)) {           // defer-max (T13): P <= 2^8 otherwise
            float mnew = fmaxf(m_s, mx);
            float alpha = exp2_hw(m_s - mnew);
            m_s = mnew;
            l_s *= alpha;
#pragma unroll
            for (int dt = 0; dt < 4; dt++) o[dt] *= alpha;
        }

        // P = 2^(S-m): exp + cvt_pk + permlane32_swap -> bf16 B-frags fully in-register
        float rs = 0.f;
        short8 bp[2][2];
#pragma unroll
        for (int kt2 = 0; kt2 < 2; kt2++) {
            float p[16];
#pragma unroll
            for (int r = 0; r < 16; r++) p[r] = exp2_hw(sacc[kt2][r] - m_s);
#pragma unroll
            for (int r = 0; r < 16; r += 4)
                rs += (p[r] + p[r + 1]) + (p[r + 2] + p[r + 3]);
            uint32_t c0 = cvtpk(p[0], p[1]),  c1 = cvtpk(p[2], p[3]);
            uint32_t c2 = cvtpk(p[4], p[5]),  c3 = cvtpk(p[6], p[7]);
            permswap(c0, c2); permswap(c1, c3);
            union { uint32_t u[4]; short8 s; } f0 = {{c0, c1, c2, c3}};
            bp[kt2][0] = f0.s;
            uint32_t c4 = cvtpk(p[8], p[9]),   c5 = cvtpk(p[10], p[11]);
            uint32_t c6 = cvtpk(p[12], p[13]), c7 = cvtpk(p[14], p[15]);
            permswap(c4, c6); permswap(c5, c7);
            union { uint32_t u[4]; short8 s; } f1 = {{c4, c5, c6, c7}};
            bp[kt2][1] = f1.s;
        }
        l_s += xhalf_sum(rs);

        // O^T += V^T · P : A=V^T[dim][key] from LDS, B=P[key][q] in regs
        __builtin_amdgcn_s_setprio(1);
#pragma unroll
        for (int kt2 = 0; kt2 < 2; kt2++)
#pragma unroll
            for (int s = 0; s < 2; s++)
#pragma unroll
                for (int dt = 0; dt < 4; dt++) {
                    short8 av = *(const short8*)(Vl + (dt * 32 + ln) * 72 + kt2 * 32 + s * 16 + hi * 8);
                    o[dt] = __builtin_amdgcn_mfma_f32_32x32x16_bf16(av, bp[kt2][s], o[dt], 0, 0, 0);
                }
        __builtin_amdgcn_s_setprio(0);
    }

    // epilogue: C col=q=ln, row=dim=dt*32+(r&3)+8*(r>>2)+4hi -> 4-consecutive-dim packs
    float inv = 1.0f / l_s;
    u16* orow = out + (size_t)(b * S + qrow + ln) * 2048 + h * 128;
#pragma unroll
    for (int dt = 0; dt < 4; dt++)
#pragma unroll
        for (int g = 0; g < 4; g++) {
            ushort4 pk4;
            pk4.x = f2bf(o[dt][g * 4 + 0] * inv);
            pk4.y = f2bf(o[dt][g * 4 + 1] * inv);
            pk4.z = f2bf(o[dt][g * 4 + 2] * inv);
            pk4.w = f2bf(o[dt][g * 4 + 3] * inv);
            *(ushort4*)(orow + dt * 32 + g * 8 + hi * 4) = pk4;
        }
}

extern "C" void kernel_launch(void* const* d_in, const int* in_sizes, int n_in,
                              void* d_out, int out_size, void* d_ws, size_t ws_size,
                              hipStream_t stream) {
    const int B = 2, S = 2048, D = 2048, H = 16;
    const int M = B * S;                       // 4096
    const int NPpad = 3840;                    // 15 tiles of 256 (cols 3648.. are pad)
    // 1/sqrt(192) * log2(e): softmax runs in exp2 domain (folded into Wq/Wq_rope)
    const float scale = 0.07216878364870323f * 1.4426950408889634f;
    const float* x    = (const float*)d_in[0];
    const float* Wq   = (const float*)d_in[1];
    const float* Wqr  = (const float*)d_in[2];
    const float* Wkvd = (const float*)d_in[3];
    const float* Wkvu = (const float*)d_in[4];
    const float* Wkr  = (const float*)d_in[5];
    const float* Wo   = (const float*)d_in[6];

    u16* p = (u16*)d_ws;
    u16* xb     = p; p += (size_t)M * D;             // 16.8 MB
    u16* WprojT = p; p += (size_t)NPpad * 2048;      // rows: [Wq|Wqr|Wkvd|Wkr|pad]
    u16* WkvuT  = p; p += (size_t)4096 * 512;
    u16* WoT    = p; p += (size_t)2048 * 2048;
    u16* proj   = p; p += (size_t)M * NPpad;         // [q_c|q_r|c_kv|k_r|pad] row-major
    u16* kv     = p; p += (size_t)M * 4096;
    u16* v_t    = p; p += (size_t)B * H * 128 * S;
    u16* attn   = p; p += (size_t)M * 2048;

    u16* q_c = proj;                 // cols 0..2047
    u16* q_r = proj + 2048;          // cols 2048..3071
    u16* ckv = proj + 3072;          // cols 3072..3583
    u16* k_r = proj + 3584;          // cols 3584..3647 (3648.. = pad, never read)

    // 1) cast + ALL weight transposes (fused: 7 launches -> 2)
    cast_f32_bf16<<<(M * D) / 4 / 256, 256, 0, stream>>>(x, xb, M * D);
    transpose_cast_all<<<3360, 256, 0, stream>>>(Wq, Wqr, Wkvd, Wkr, Wkvu, Wo,
                                                 WprojT, WkvuT, WoT, scale);

    // 2) merged projection GEMM (128x256 ring-3, 32x32 MFMA): proj = xb @ WprojT^T
    gemm_rg<2048><<<dim3(32, 15), 256, 0, stream>>>(xb, 2048, WprojT, proj, NPpad);

    // 3) RoPE fused (q_r 16 heads + k_r): rotation linear, pre-scale commutes
    rope_all<<<(M * 17 * 32) / 256, 256, 0, stream>>>(q_r, M, S - 1, NPpad);

    // 4) kv up-projection (128x256 ring-3, 32x32 MFMA), V transpose
    gemm_rg<512><<<dim3(32, 16), 256, 0, stream>>>(ckv, NPpad, WkvuT, kv, 4096);
    transpose_v<<<dim3(32, 2, 32), 256, 0, stream>>>(kv, v_t, S);

    // 5) attention — grid (bh, 16 q-tiles of 128): pair-balanced, XCD/CU-pinned
    mla_attn<<<dim3(32, 16), 256, 0, stream>>>(q_c, NPpad, q_r, NPpad, kv, k_r, NPpad,
                                               v_t, attn, S);

    // 6) output projection -> fp32 d_out
    gemm_bt<1, 2048, 2048><<<dim3(32, 16), 256, 0, stream>>>(attn, 2048, WoT, d_out, 2048);
}